// Round 2
// baseline (918.349 us; speedup 1.0000x reference)
//
#include <hip/hip_runtime.h>
#include <stdint.h>

// Problem constants
#define N_TOK 65536
#define DIN   512
#define DH    1024
#define DOUT  512
#define NE    8
#define MP_CAP 66560     // padded row space capacity (N + 8*128, /128)
#define ROW_BLOCKS 520   // MP_CAP / 128
#define CSTRIDE 144      // epilogue C-stage LDS row stride (ushorts): bank-conflict-free

typedef __bf16 bf16x8 __attribute__((ext_vector_type(8)));
typedef float  f32x4  __attribute__((ext_vector_type(4)));

// address-space-qualified pointer types for global_load_lds
typedef __attribute__((address_space(3))) void  lds_void;
typedef const __attribute__((address_space(1))) void g_void;

__device__ __forceinline__ float bf2f(unsigned short u) {
  union { unsigned int i; float f; } v; v.i = ((unsigned int)u) << 16; return v.f;
}
__device__ __forceinline__ unsigned short f2bf(float f) {
  unsigned int u = __builtin_bit_cast(unsigned int, f);
  u += 0x7fffu + ((u >> 16) & 1u);      // RNE
  return (unsigned short)(u >> 16);
}

// ---------------- dtype probe + zero counts/fill (fp32-read-as-ushort has wild exps) --------
__global__ void detect_k(const unsigned short* __restrict__ x, int* __restrict__ flag,
                         int* __restrict__ counts, int* __restrict__ fill) {
  __shared__ int cnt;
  if (threadIdx.x < 8) { counts[threadIdx.x] = 0; fill[threadIdx.x] = 0; }
  if (threadIdx.x == 0) cnt = 0;
  __syncthreads();
  int c = 0;
  for (int i = threadIdx.x; i < 16384; i += 256) {
    const unsigned short u = x[2 * i];
    const int ex = (u >> 7) & 0xFF;
    if (ex > 140) ++c;
  }
  atomicAdd(&cnt, c);
  __syncthreads();
  if (threadIdx.x == 0) flag[0] = (cnt > 512) ? 1 : 0;   // 1 = inputs are fp32
}

// ---------------- biases -> fp32  +  rowmap = -1 fill (fused) ----------------
__global__ __launch_bounds__(256)
void prep_k(const void* __restrict__ b0, const void* __restrict__ b1,
            const void* __restrict__ b2, float* __restrict__ bf0,
            float* __restrict__ bf1, float* __restrict__ bf2,
            int* __restrict__ rowmap, const int* __restrict__ flag) {
  const int b = blockIdx.x;
  if (b < 65) {                       // rowmap: 66560 ints = 65 blocks * 256 * int4
    const int i = (b * 256 + threadIdx.x) * 4;
    *(int4*)&rowmap[i] = (int4){-1, -1, -1, -1};
    return;
  }
  const int fv = flag[0];
  const int i = (b - 65) * 256 + threadIdx.x;   // 0..20479
  const void* src; float* dst; int li;
  if (i < NE * DH) { src = b0; dst = bf0; li = i; }
  else if (i < 2 * NE * DH) { src = b1; dst = bf1; li = i - NE * DH; }
  else { src = b2; dst = bf2; li = i - 2 * NE * DH; }
  dst[li] = fv ? ((const float*)src)[li] : bf2f(((const unsigned short*)src)[li]);
}

// ---------------- all three weight transposes in one launch ----------------
// W[e][K][Nn] -> WT[e][Nn][K] (bf16 out); tile decode from 1-D grid.
__global__ __launch_bounds__(1024)
void transpose_all_k(const void* __restrict__ W0, const void* __restrict__ W1,
                     const void* __restrict__ W2, unsigned short* __restrict__ WT0,
                     unsigned short* __restrict__ WT1, unsigned short* __restrict__ WT2,
                     const int* __restrict__ flag) {
  __shared__ unsigned short tile[64][65];
  const int fv = flag[0];
  int b = blockIdx.x;
  const void* W; unsigned short* WT; int K, Nn, e, n0, k0;
  if (b < 1024) {            // W0: per-expert 16 n-tiles x 8 k-tiles
    W = W0; WT = WT0; K = DIN; Nn = DH;
    e = b >> 7; const int r = b & 127; n0 = (r & 15) * 64; k0 = (r >> 4) * 64;
  } else if (b < 3072) {     // W1: 16 x 16
    b -= 1024; W = W1; WT = WT1; K = DH; Nn = DH;
    e = b >> 8; const int r = b & 255; n0 = (r & 15) * 64; k0 = (r >> 4) * 64;
  } else {                   // W2: 8 n-tiles x 16 k-tiles
    b -= 3072; W = W2; WT = WT2; K = DH; Nn = DOUT;
    e = b >> 7; const int r = b & 127; n0 = (r & 7) * 64; k0 = (r >> 3) * 64;
  }
  const size_t base = (size_t)e * K * Nn;
  unsigned short* dst = WT + base;
  const int tx = threadIdx.x & 63, ty = threadIdx.x >> 6;
#pragma unroll
  for (int i = 0; i < 4; ++i) {
    const size_t idx = base + (size_t)(k0 + ty + i * 16) * Nn + n0 + tx;
    tile[ty + i * 16][tx] = fv ? f2bf(((const float*)W)[idx])
                               : ((const unsigned short*)W)[idx];
  }
  __syncthreads();
#pragma unroll
  for (int i = 0; i < 4; ++i)
    dst[(size_t)(n0 + ty + i * 16) * K + k0 + tx] = tile[tx][ty + i * 16];
}

// ---------------- fused gating: logits(fp64) + argmax + xc(bf16) + counts ----------------
// One wave per token. Wg staged to LDS transposed [e][k] so the inner-loop read is
// stride-1 across lanes (conflict-free) instead of a 32B-stride global gather (the old
// pattern split every wave load into ~16 transactions). fp64 accumulation order is
// bit-identical to the previous (passing) gating_k: per lane k = i*64+lane, tree reduce.
__global__ __launch_bounds__(256)
void gating_fused_k(const void* __restrict__ x, const void* __restrict__ Wg,
                    const void* __restrict__ bg, unsigned short* __restrict__ xc,
                    int* __restrict__ eidx, int* __restrict__ counts,
                    const int* __restrict__ flag) {
  __shared__ float wgT[NE * DIN];     // [e][k], 16 KB
  __shared__ int hist[8];
  const int tid = threadIdx.x;
  const int fv = flag[0];
  if (tid < 8) hist[tid] = 0;
  if (fv) {
    const float* wg = (const float*)Wg;
    for (int idx = tid; idx < NE * DIN; idx += 256) {
      const int k = idx >> 3, e = idx & 7;
      wgT[e * DIN + k] = wg[idx];
    }
  } else {
    const unsigned short* wg = (const unsigned short*)Wg;
    for (int idx = tid; idx < NE * DIN; idx += 256) {
      const int k = idx >> 3, e = idx & 7;
      wgT[e * DIN + k] = bf2f(wg[idx]);
    }
  }
  __syncthreads();

  const int wv = tid >> 6, lane = tid & 63;
  const int t = blockIdx.x * 4 + wv;
  double acc[8];
#pragma unroll
  for (int e = 0; e < 8; ++e) acc[e] = 0.0;

  if (fv) {
    const float* xr = (const float*)x + (size_t)t * DIN;
    float xs[8];
#pragma unroll
    for (int i = 0; i < 8; ++i) {
      const int k = i * 64 + lane;
      const float xf = xr[k];
      xs[i] = xf;
      const double xv = (double)xf;
#pragma unroll
      for (int e = 0; e < 8; ++e) acc[e] += xv * (double)wgT[e * DIN + k];
    }
    unsigned short* xo = xc + (size_t)t * DIN;   // bf16 canonical copy (coalesced 128B/wave)
#pragma unroll
    for (int i = 0; i < 8; ++i) xo[i * 64 + lane] = f2bf(xs[i]);
  } else {
    const unsigned short* xr = (const unsigned short*)x + (size_t)t * DIN;
#pragma unroll
    for (int i = 0; i < 8; ++i) {
      const int k = i * 64 + lane;
      const double xv = (double)bf2f(xr[k]);
#pragma unroll
      for (int e = 0; e < 8; ++e) acc[e] += xv * (double)wgT[e * DIN + k];
    }
  }
#pragma unroll
  for (int o = 32; o > 0; o >>= 1)
#pragma unroll
    for (int e = 0; e < 8; ++e) acc[e] += __shfl_down(acc[e], o, 64);
  if (lane == 0) {
    int bi = 0;
    double best = acc[0] + (double)(fv ? ((const float*)bg)[0]
                                       : bf2f(((const unsigned short*)bg)[0]));
#pragma unroll
    for (int e = 1; e < 8; ++e) {
      const double v = acc[e] + (double)(fv ? ((const float*)bg)[e]
                                            : bf2f(((const unsigned short*)bg)[e]));
      if (v > best) { best = v; bi = e; }   // strict >: first-max wins (np.argmax)
    }
    eidx[t] = bi;
    atomicAdd(&hist[bi], 1);
  }
  __syncthreads();
  if (tid < 8 && hist[tid]) atomicAdd(&counts[tid], hist[tid]);
}

// ---------------- scatter tokens into rowmap (local prefix from counts) ----------------
__global__ __launch_bounds__(256)
void scatter_k(const int* __restrict__ eidx, const int* __restrict__ counts,
               int* __restrict__ off_g, int* __restrict__ fill,
               int* __restrict__ rowmap) {
  int off[8];
  {
    int a = 0;
#pragma unroll
    for (int e2 = 0; e2 < 8; ++e2) { off[e2] = a; a += (counts[e2] + 127) & ~127; }
    if (blockIdx.x == 0 && threadIdx.x == 0) {
      off_g[0] = 0;
      int aa = 0;
#pragma unroll
      for (int e2 = 0; e2 < 8; ++e2) { aa += (counts[e2] + 127) & ~127; off_g[e2 + 1] = aa; }
    }
  }
  const int t = blockIdx.x * 256 + threadIdx.x;
  const int lane = threadIdx.x & 63;
  const int e = eidx[t];
#pragma unroll
  for (int ex = 0; ex < 8; ++ex) {
    unsigned long long m = __ballot(e == ex);
    if (e == ex) {
      const unsigned long long lt = (1ULL << lane) - 1ULL;
      const int rank = __popcll(m & lt);
      const int leader = __ffsll((unsigned long long)m) - 1;
      int base = 0;
      if (lane == leader) base = atomicAdd(&fill[ex], (int)__popcll(m));
      base = __shfl(base, leader, 64);
      rowmap[off[ex] + base + rank] = t;
    }
  }
}

// ---------------- grouped GEMM: C[128 x 128] per block, K-step 64 ----------------
// (unchanged from previous round — global_load_lds width=16, Rule-21 swizzle)
template <int GATHER, int RELU, int SCATTER>
__global__ __launch_bounds__(256, 2)
void gemm_k(const unsigned short* __restrict__ A, const unsigned short* __restrict__ Axc,
            const unsigned short* __restrict__ BT,
            const float* __restrict__ biasF, void* __restrict__ C,
            const int* __restrict__ rowmap, const int* __restrict__ off,
            const int* __restrict__ flag, const int K, const int Nc, const int rowBase,
            const int ncb, const int lncb) {
  __shared__ __align__(16) unsigned short smem[128 * CSTRIDE];  // 36 KB
  unsigned short* As = smem;                 // staging: 128x64 = 16 KB
  unsigned short* Bs = smem + 128 * 64;      // staging: 128x64 = 16 KB

  // ---- swizzled block -> (rowg, col) ----
  const int segBlocksLocal = gridDim.x >> lncb;
  const int fullRows = segBlocksLocal & ~7;
  const int fullBlocks = fullRows << lncb;
  int col, rowg;
  {
    const int p = blockIdx.x;
    if (p < fullBlocks) {
      const int xcd = p & 7, qq = p >> 3;
      col = qq & (ncb - 1);
      rowg = ((qq >> lncb) << 3) + xcd;
    } else {
      const int r = p - fullBlocks;
      col = r & (ncb - 1);
      rowg = fullRows + (r >> lncb);
    }
  }

  const int Mp = off[8];
  const int rowStart = rowBase + rowg * 128;
  if (rowStart >= Mp) return;
  int e = 0;
#pragma unroll
  for (int j = 1; j <= 8; ++j) e += (off[j] <= rowStart) ? 1 : 0;

  const int colStart = col * 128;
  const int tid = threadIdx.x;
  const int w = tid >> 6, lane = tid & 63;
  const int subrow = lane >> 3;
  const int q = lane & 7;
  const int slot = q ^ subrow;               // inverse-swizzled global chunk index

  const unsigned short* Ause = (GATHER && flag[0]) ? Axc : A;
  const unsigned short* Be = BT + (size_t)e * Nc * K;

  // per-lane global source pointers (chunk `slot`), wave-uniform LDS dest offsets
  const unsigned short* aptr[4];
  const unsigned short* bptr[4];
  int ldsOff[4];
#pragma unroll
  for (int i = 0; i < 4; ++i) {
    const int r = i * 32 + w * 8 + subrow;
    int arow;
    if (GATHER) {
      arow = rowmap[rowStart + r];
      if (arow < 0) arow = 0;                 // padding row: load safe garbage
    } else {
      arow = rowStart + r - rowBase;          // segment-local
    }
    aptr[i] = Ause + (size_t)arow * K + slot * 8;
    bptr[i] = Be + (size_t)(colStart + r) * K + slot * 8;
    ldsOff[i] = (i * 32 + w * 8) * 64;        // linear dest: 8 rows x 128 B per call
  }

  const int wm = w >> 1, wn = w & 1;
  const int fr = lane & 15, quad = lane >> 4;

  f32x4 acc[4][4];
#pragma unroll
  for (int i = 0; i < 4; ++i)
#pragma unroll
    for (int j = 0; j < 4; ++j) acc[i][j] = (f32x4){0.f, 0.f, 0.f, 0.f};

  int aoff[2][4], boff[2][4];
#pragma unroll
  for (int s = 0; s < 2; ++s)
#pragma unroll
    for (int i = 0; i < 4; ++i) {
      const int qq = quad + s * 4;
      const int rowA = wm * 64 + i * 16 + fr;
      aoff[s][i] = rowA * 64 + (qq ^ (rowA & 7)) * 8;
      const int rowB = wn * 64 + i * 16 + fr;
      boff[s][i] = rowB * 64 + (qq ^ (rowB & 7)) * 8;
    }

  for (int k0 = 0; k0 < K; k0 += 64) {
    // async global -> LDS staging (this K-step's tile). Prior iteration's trailing
    // barrier guarantees all LDS reads of the previous tile completed.
#pragma unroll
    for (int i = 0; i < 4; ++i) {
      __builtin_amdgcn_global_load_lds((g_void*)(aptr[i] + k0),
                                       (lds_void*)(As + ldsOff[i]), 16, 0, 0);
      __builtin_amdgcn_global_load_lds((g_void*)(bptr[i] + k0),
                                       (lds_void*)(Bs + ldsOff[i]), 16, 0, 0);
    }
    __syncthreads();                          // vmcnt(0) drain -> tile visible to all
    bf16x8 af[2][4], bfv[2][4];
#pragma unroll
    for (int s = 0; s < 2; ++s)
#pragma unroll
      for (int i = 0; i < 4; ++i) {
        af[s][i] = *(const bf16x8*)&As[aoff[s][i]];
        bfv[s][i] = *(const bf16x8*)&Bs[boff[s][i]];
      }
#pragma unroll
    for (int s = 0; s < 2; ++s)
#pragma unroll
      for (int i = 0; i < 4; ++i)
#pragma unroll
        for (int j = 0; j < 4; ++j)
          acc[i][j] = __builtin_amdgcn_mfma_f32_16x16x32_bf16(af[s][i], bfv[s][j],
                                                              acc[i][j], 0, 0, 0);
    __syncthreads();                          // reads done before next overwrite
  }

  // ---- epilogue ----
  const int flagv = SCATTER ? flag[0] : 0;
  float bv2[4];
#pragma unroll
  for (int j = 0; j < 4; ++j)
    bv2[j] = biasF[(size_t)e * Nc + colStart + wn * 64 + j * 16 + fr];

  if (SCATTER && flagv) {
    // rare fp32-output path: exact scalar stores from acc
#pragma unroll
    for (int i = 0; i < 4; ++i)
#pragma unroll
      for (int r = 0; r < 4; ++r) {
        const int gr = rowStart + wm * 64 + i * 16 + quad * 4 + r;
        const int crow = rowmap[gr];
        if (crow < 0) continue;
        const size_t cbase = (size_t)crow * Nc + colStart + wn * 64 + fr;
#pragma unroll
        for (int j = 0; j < 4; ++j)
          ((float*)C)[cbase + j * 16] = acc[i][j][r] + bv2[j];
      }
    return;
  }

  __syncthreads();
#pragma unroll
  for (int i = 0; i < 4; ++i)
#pragma unroll
    for (int r = 0; r < 4; ++r) {
      const int row = wm * 64 + i * 16 + quad * 4 + r;   // C/D: row=(lane>>4)*4+reg
#pragma unroll
      for (int j = 0; j < 4; ++j) {
        float v = acc[i][j][r] + bv2[j];
        if (RELU) v = fmaxf(v, 0.f);
        smem[row * CSTRIDE + wn * 64 + j * 16 + fr] = f2bf(v);
      }
    }
  __syncthreads();

#pragma unroll
  for (int it = 0; it < 8; ++it) {
    const int idx = it * 256 + tid;
    const int row = idx >> 4, c16 = idx & 15;
    int crow;
    if (SCATTER) {
      crow = rowmap[rowStart + row];
      if (crow < 0) continue;                 // padding row
    } else {
      crow = rowStart + row - rowBase;        // segment-local
    }
    const uint4 vv = *(const uint4*)&smem[row * CSTRIDE + c16 * 8];
    *(uint4*)&((unsigned short*)C)[(size_t)crow * Nc + colStart + c16 * 8] = vv;
  }
}

extern "C" void kernel_launch(void* const* d_in, const int* in_sizes, int n_in,
                              void* d_out, int out_size, void* d_ws, size_t ws_size,
                              hipStream_t stream) {
  const void* x  = d_in[0];
  const void* Wg = d_in[1];
  const void* bg = d_in[2];
  const void* W0 = d_in[3];
  const void* b0 = d_in[4];
  const void* W1 = d_in[5];
  const void* b1 = d_in[6];
  const void* W2 = d_in[7];
  const void* b2 = d_in[8];

  char* ws = (char*)d_ws;
  // fixed workspace layout (~101.3 MB) + adaptive h0/h1
  unsigned short* WT0 = (unsigned short*)(ws + 0);            //  8 MB [E][DH][DIN]
  unsigned short* WT1 = (unsigned short*)(ws + 8388608);      // 16 MB [E][DH][DH]
  unsigned short* WT2 = (unsigned short*)(ws + 25165824);     //  8 MB [E][DOUT][DH]
  unsigned short* xc  = (unsigned short*)(ws + 33554432);     // 64 MB [N][DIN] bf16 (flag=1 only)
  float* bf0 = (float*)(ws + 100663296);
  float* bf1 = (float*)(ws + 100696064);
  float* bf2 = (float*)(ws + 100728832);
  int* rowmap = (int*)(ws + 100745216);                       // MP_CAP ints
  int* eidx   = (int*)(ws + 101011456);                       // N ints
  int* counts = (int*)(ws + 101273600);
  int* off    = (int*)(ws + 101273664);
  int* fill   = (int*)(ws + 101273728);
  int* flag   = (int*)(ws + 101273792);
  const size_t FIXED = 101274624;
  unsigned short* h0 = (unsigned short*)(ws + FIXED);

  // segment sizing: h0+h1 = segBlocks * 524288 B; prefer multiples of 8 for the swizzle
  int segBlocks = 1;
  if (ws_size > FIXED + 524288) {
    size_t sb = (ws_size - FIXED) / 524288;
    segBlocks = (sb > ROW_BLOCKS) ? ROW_BLOCKS : (int)sb;
    if (segBlocks >= 8) segBlocks &= ~7;
  }
  unsigned short* h1 = h0 + (size_t)segBlocks * 128 * DH;
  const int nseg = (ROW_BLOCKS + segBlocks - 1) / segBlocks;

  detect_k<<<1, 256, 0, stream>>>((const unsigned short*)x, flag, counts, fill);

  prep_k<<<65 + (3 * NE * DH - NE * DH + NE * DOUT + NE * DH + 255) / 256, 256, 0, stream>>>(
      b0, b1, b2, bf0, bf1, bf2, rowmap, flag);   // 65 rowmap blocks + 80 bias blocks

  transpose_all_k<<<4096, 1024, 0, stream>>>(W0, W1, W2, WT0, WT1, WT2, flag);

  gating_fused_k<<<N_TOK / 4, 256, 0, stream>>>(x, Wg, bg, xc, eidx, counts, flag);

  scatter_k<<<N_TOK / 256, 256, 0, stream>>>(eidx, counts, off, fill, rowmap);

  for (int s = 0; s < nseg; ++s) {
    const int rowBase = s * segBlocks * 128;
    // layer 0: gather x rows -> h0 (relu); ncb = DH/128 = 8
    gemm_k<1, 1, 0><<<dim3(8 * segBlocks), 256, 0, stream>>>(
        (const unsigned short*)x, xc, WT0, bf0, h0, rowmap, off, flag, DIN, DH, rowBase, 8, 3);
    // layer 1: h0 -> h1 (relu); ncb = 8
    gemm_k<0, 1, 0><<<dim3(8 * segBlocks), 256, 0, stream>>>(
        h0, h0, WT1, bf1, h1, rowmap, off, flag, DH, DH, rowBase, 8, 3);
    // layer 2: h1 -> out (scatter, bias only); ncb = DOUT/128 = 4
    gemm_k<0, 0, 1><<<dim3(4 * segBlocks), 256, 0, stream>>>(
        h1, h1, WT2, bf2, d_out, rowmap, off, flag, DH, DOUT, rowBase, 4, 2);
  }
}

// Round 4
// 917.131 us; speedup vs baseline: 1.0013x; 1.0013x over previous
//
#include <hip/hip_runtime.h>
#include <stdint.h>

// Problem constants
#define N_TOK 65536
#define DIN   512
#define DH    1024
#define DOUT  512
#define NE    8
#define MP_CAP 66560     // padded row space capacity (N + 8*128, /128)
#define ROW_BLOCKS 520   // MP_CAP / 128
#define CSTRIDE 144      // epilogue C-stage LDS row stride (ushorts): bank-conflict-free

typedef __bf16 bf16x8 __attribute__((ext_vector_type(8)));
typedef float  f32x4  __attribute__((ext_vector_type(4)));

// address-space-qualified pointer types for global_load_lds
typedef __attribute__((address_space(3))) void  lds_void;
typedef const __attribute__((address_space(1))) void g_void;

__device__ __forceinline__ float bf2f(unsigned short u) {
  union { unsigned int i; float f; } v; v.i = ((unsigned int)u) << 16; return v.f;
}
__device__ __forceinline__ unsigned short f2bf(float f) {
  unsigned int u = __builtin_bit_cast(unsigned int, f);
  u += 0x7fffu + ((u >> 16) & 1u);      // RNE
  return (unsigned short)(u >> 16);
}

// ---------------- dtype probe + zero counts/fill (fp32-read-as-ushort has wild exps) --------
__global__ void detect_k(const unsigned short* __restrict__ x, int* __restrict__ flag,
                         int* __restrict__ counts, int* __restrict__ fill) {
  __shared__ int cnt;
  if (threadIdx.x < 8) { counts[threadIdx.x] = 0; fill[threadIdx.x] = 0; }
  if (threadIdx.x == 0) cnt = 0;
  __syncthreads();
  int c = 0;
  for (int i = threadIdx.x; i < 16384; i += 256) {
    const unsigned short u = x[2 * i];
    const int ex = (u >> 7) & 0xFF;
    if (ex > 140) ++c;
  }
  atomicAdd(&cnt, c);
  __syncthreads();
  if (threadIdx.x == 0) flag[0] = (cnt > 512) ? 1 : 0;   // 1 = inputs are fp32
}

// ------- prep: biases -> fp32, rowmap = -1 fill, Wg -> wgF[e][k] f32 (transposed) -------
__global__ __launch_bounds__(256)
void prep_k(const void* __restrict__ b0, const void* __restrict__ b1,
            const void* __restrict__ b2, float* __restrict__ bf0,
            float* __restrict__ bf1, float* __restrict__ bf2,
            int* __restrict__ rowmap, const void* __restrict__ Wg,
            float* __restrict__ wgF, const int* __restrict__ flag) {
  const int b = blockIdx.x;
  if (b < 65) {                       // rowmap: 66560 ints = 65 blocks * 256 * int4
    const int i = (b * 256 + threadIdx.x) * 4;
    *(int4*)&rowmap[i] = (int4){-1, -1, -1, -1};
    return;
  }
  const int fv = flag[0];
  if (b < 145) {                      // biases: 20480 elements
    const int i = (b - 65) * 256 + threadIdx.x;
    const void* src; float* dst; int li;
    if (i < NE * DH) { src = b0; dst = bf0; li = i; }
    else if (i < 2 * NE * DH) { src = b1; dst = bf1; li = i - NE * DH; }
    else { src = b2; dst = bf2; li = i - 2 * NE * DH; }
    dst[li] = fv ? ((const float*)src)[li] : bf2f(((const unsigned short*)src)[li]);
    return;
  }
  // wgF[e][k] = Wg[k][e], f32: 4096 elements in 16 blocks
  const int idx = (b - 145) * 256 + threadIdx.x;
  const int e = idx >> 9, k = idx & 511;
  wgF[idx] = fv ? ((const float*)Wg)[k * 8 + e]
                : bf2f(((const unsigned short*)Wg)[k * 8 + e]);
}

// ---------------- all three weight transposes in one launch ----------------
// W[e][K][Nn] -> WT[e][Nn][K] (bf16 out); tile decode from 1-D grid.
__global__ __launch_bounds__(1024)
void transpose_all_k(const void* __restrict__ W0, const void* __restrict__ W1,
                     const void* __restrict__ W2, unsigned short* __restrict__ WT0,
                     unsigned short* __restrict__ WT1, unsigned short* __restrict__ WT2,
                     const int* __restrict__ flag) {
  __shared__ unsigned short tile[64][65];
  const int fv = flag[0];
  int b = blockIdx.x;
  const void* W; unsigned short* WT; int K, Nn, e, n0, k0;
  if (b < 1024) {            // W0: per-expert 16 n-tiles x 8 k-tiles
    W = W0; WT = WT0; K = DIN; Nn = DH;
    e = b >> 7; const int r = b & 127; n0 = (r & 15) * 64; k0 = (r >> 4) * 64;
  } else if (b < 3072) {     // W1: 16 x 16
    b -= 1024; W = W1; WT = WT1; K = DH; Nn = DH;
    e = b >> 8; const int r = b & 255; n0 = (r & 15) * 64; k0 = (r >> 4) * 64;
  } else {                   // W2: 8 n-tiles x 16 k-tiles
    b -= 3072; W = W2; WT = WT2; K = DH; Nn = DOUT;
    e = b >> 7; const int r = b & 127; n0 = (r & 7) * 64; k0 = (r >> 3) * 64;
  }
  const size_t base = (size_t)e * K * Nn;
  unsigned short* dst = WT + base;
  const int tx = threadIdx.x & 63, ty = threadIdx.x >> 6;
#pragma unroll
  for (int i = 0; i < 4; ++i) {
    const size_t idx = base + (size_t)(k0 + ty + i * 16) * Nn + n0 + tx;
    tile[ty + i * 16][tx] = fv ? f2bf(((const float*)W)[idx])
                               : ((const unsigned short*)W)[idx];
  }
  __syncthreads();
#pragma unroll
  for (int i = 0; i < 4; ++i)
    dst[(size_t)(n0 + ty + i * 16) * K + k0 + tx] = tile[tx][ty + i * 16];
}

// ---------------- fused gating: logits(fp64) + argmax + xc(bf16) + counts ----------------
// One wave per token. Wg read from the prep-transposed global wgF[e][k] f32 table:
// for fixed e, 64 lanes read 256 consecutive bytes (coalesced, 16 KB L1-resident).
// No LDS table (round-2's wgT had 2048B row stride -> all-8-experts-same-bank conflicts).
// fp64 accumulation order is bit-identical to the passing rounds: per lane k = i*64+lane,
// i ascending, shfl_down tree reduce, strict-> serial argmax (np.argmax first-max).
__global__ __launch_bounds__(256)
void gating_k(const void* __restrict__ x, const float* __restrict__ wgF,
              const void* __restrict__ bg, unsigned short* __restrict__ xc,
              int* __restrict__ eidx, int* __restrict__ counts,
              const int* __restrict__ flag) {
  __shared__ int hist[8];
  const int tid = threadIdx.x;
  if (tid < 8) hist[tid] = 0;
  __syncthreads();

  const int wv = tid >> 6, lane = tid & 63;
  const int t = blockIdx.x * 4 + wv;
  const int fv = flag[0];
  double acc[8];
#pragma unroll
  for (int e = 0; e < 8; ++e) acc[e] = 0.0;

  if (fv) {
    const float* xr = (const float*)x + (size_t)t * DIN;
    unsigned short* xo = xc + (size_t)t * DIN;
#pragma unroll
    for (int i = 0; i < 8; ++i) {
      const int k = i * 64 + lane;
      const float xf = xr[k];
      const double xv = (double)xf;
#pragma unroll
      for (int e = 0; e < 8; ++e) acc[e] += xv * (double)wgF[e * DIN + k];
      xo[k] = f2bf(xf);                     // fused bf16 canonical copy (coalesced)
    }
  } else {
    const unsigned short* xr = (const unsigned short*)x + (size_t)t * DIN;
#pragma unroll
    for (int i = 0; i < 8; ++i) {
      const int k = i * 64 + lane;
      const double xv = (double)bf2f(xr[k]);
#pragma unroll
      for (int e = 0; e < 8; ++e) acc[e] += xv * (double)wgF[e * DIN + k];
    }
  }
#pragma unroll
  for (int o = 32; o > 0; o >>= 1)
#pragma unroll
    for (int e = 0; e < 8; ++e) acc[e] += __shfl_down(acc[e], o, 64);
  if (lane == 0) {
    int bi = 0;
    double best = acc[0] + (double)(fv ? ((const float*)bg)[0]
                                       : bf2f(((const unsigned short*)bg)[0]));
#pragma unroll
    for (int e = 1; e < 8; ++e) {
      const double v = acc[e] + (double)(fv ? ((const float*)bg)[e]
                                            : bf2f(((const unsigned short*)bg)[e]));
      if (v > best) { best = v; bi = e; }   // strict >: first-max wins (np.argmax)
    }
    eidx[t] = bi;
    atomicAdd(&hist[bi], 1);
  }
  __syncthreads();
  if (tid < 8 && hist[tid]) atomicAdd(&counts[tid], hist[tid]);
}

// ---------------- scatter tokens into rowmap (local prefix from counts) ----------------
__global__ __launch_bounds__(256)
void scatter_k(const int* __restrict__ eidx, const int* __restrict__ counts,
               int* __restrict__ off_g, int* __restrict__ fill,
               int* __restrict__ rowmap) {
  int off[8];
  {
    int a = 0;
#pragma unroll
    for (int e2 = 0; e2 < 8; ++e2) { off[e2] = a; a += (counts[e2] + 127) & ~127; }
    if (blockIdx.x == 0 && threadIdx.x == 0) {
      off_g[0] = 0;
      int aa = 0;
#pragma unroll
      for (int e2 = 0; e2 < 8; ++e2) { aa += (counts[e2] + 127) & ~127; off_g[e2 + 1] = aa; }
    }
  }
  const int t = blockIdx.x * 256 + threadIdx.x;
  const int lane = threadIdx.x & 63;
  const int e = eidx[t];
#pragma unroll
  for (int ex = 0; ex < 8; ++ex) {
    unsigned long long m = __ballot(e == ex);
    if (e == ex) {
      const unsigned long long lt = (1ULL << lane) - 1ULL;
      const int rank = __popcll(m & lt);
      const int leader = __ffsll((unsigned long long)m) - 1;
      int base = 0;
      if (lane == leader) base = atomicAdd(&fill[ex], (int)__popcll(m));
      base = __shfl(base, leader, 64);
      rowmap[off[ex] + base + rank] = t;
    }
  }
}

// ---------------- grouped GEMM: C[128 x 128] per block, K-step 64 ----------------
// (unchanged — global_load_lds width=16, Rule-21 swizzle)
template <int GATHER, int RELU, int SCATTER>
__global__ __launch_bounds__(256, 2)
void gemm_k(const unsigned short* __restrict__ A, const unsigned short* __restrict__ Axc,
            const unsigned short* __restrict__ BT,
            const float* __restrict__ biasF, void* __restrict__ C,
            const int* __restrict__ rowmap, const int* __restrict__ off,
            const int* __restrict__ flag, const int K, const int Nc, const int rowBase,
            const int ncb, const int lncb) {
  __shared__ __align__(16) unsigned short smem[128 * CSTRIDE];  // 36 KB
  unsigned short* As = smem;                 // staging: 128x64 = 16 KB
  unsigned short* Bs = smem + 128 * 64;      // staging: 128x64 = 16 KB

  // ---- swizzled block -> (rowg, col) ----
  const int segBlocksLocal = gridDim.x >> lncb;
  const int fullRows = segBlocksLocal & ~7;
  const int fullBlocks = fullRows << lncb;
  int col, rowg;
  {
    const int p = blockIdx.x;
    if (p < fullBlocks) {
      const int xcd = p & 7, qq = p >> 3;
      col = qq & (ncb - 1);
      rowg = ((qq >> lncb) << 3) + xcd;
    } else {
      const int r = p - fullBlocks;
      col = r & (ncb - 1);
      rowg = fullRows + (r >> lncb);
    }
  }

  const int Mp = off[8];
  const int rowStart = rowBase + rowg * 128;
  if (rowStart >= Mp) return;
  int e = 0;
#pragma unroll
  for (int j = 1; j <= 8; ++j) e += (off[j] <= rowStart) ? 1 : 0;

  const int colStart = col * 128;
  const int tid = threadIdx.x;
  const int w = tid >> 6, lane = tid & 63;
  const int subrow = lane >> 3;
  const int q = lane & 7;
  const int slot = q ^ subrow;               // inverse-swizzled global chunk index

  const unsigned short* Ause = (GATHER && flag[0]) ? Axc : A;
  const unsigned short* Be = BT + (size_t)e * Nc * K;

  // per-lane global source pointers (chunk `slot`), wave-uniform LDS dest offsets
  const unsigned short* aptr[4];
  const unsigned short* bptr[4];
  int ldsOff[4];
#pragma unroll
  for (int i = 0; i < 4; ++i) {
    const int r = i * 32 + w * 8 + subrow;
    int arow;
    if (GATHER) {
      arow = rowmap[rowStart + r];
      if (arow < 0) arow = 0;                 // padding row: load safe garbage
    } else {
      arow = rowStart + r - rowBase;          // segment-local
    }
    aptr[i] = Ause + (size_t)arow * K + slot * 8;
    bptr[i] = Be + (size_t)(colStart + r) * K + slot * 8;
    ldsOff[i] = (i * 32 + w * 8) * 64;        // linear dest: 8 rows x 128 B per call
  }

  const int wm = w >> 1, wn = w & 1;
  const int fr = lane & 15, quad = lane >> 4;

  f32x4 acc[4][4];
#pragma unroll
  for (int i = 0; i < 4; ++i)
#pragma unroll
    for (int j = 0; j < 4; ++j) acc[i][j] = (f32x4){0.f, 0.f, 0.f, 0.f};

  int aoff[2][4], boff[2][4];
#pragma unroll
  for (int s = 0; s < 2; ++s)
#pragma unroll
    for (int i = 0; i < 4; ++i) {
      const int qq = quad + s * 4;
      const int rowA = wm * 64 + i * 16 + fr;
      aoff[s][i] = rowA * 64 + (qq ^ (rowA & 7)) * 8;
      const int rowB = wn * 64 + i * 16 + fr;
      boff[s][i] = rowB * 64 + (qq ^ (rowB & 7)) * 8;
    }

  for (int k0 = 0; k0 < K; k0 += 64) {
    // async global -> LDS staging (this K-step's tile). Prior iteration's trailing
    // barrier guarantees all LDS reads of the previous tile completed.
#pragma unroll
    for (int i = 0; i < 4; ++i) {
      __builtin_amdgcn_global_load_lds((g_void*)(aptr[i] + k0),
                                       (lds_void*)(As + ldsOff[i]), 16, 0, 0);
      __builtin_amdgcn_global_load_lds((g_void*)(bptr[i] + k0),
                                       (lds_void*)(Bs + ldsOff[i]), 16, 0, 0);
    }
    __syncthreads();                          // vmcnt(0) drain -> tile visible to all
    bf16x8 af[2][4], bfv[2][4];
#pragma unroll
    for (int s = 0; s < 2; ++s)
#pragma unroll
      for (int i = 0; i < 4; ++i) {
        af[s][i] = *(const bf16x8*)&As[aoff[s][i]];
        bfv[s][i] = *(const bf16x8*)&Bs[boff[s][i]];
      }
#pragma unroll
    for (int s = 0; s < 2; ++s)
#pragma unroll
      for (int i = 0; i < 4; ++i)
#pragma unroll
        for (int j = 0; j < 4; ++j)
          acc[i][j] = __builtin_amdgcn_mfma_f32_16x16x32_bf16(af[s][i], bfv[s][j],
                                                              acc[i][j], 0, 0, 0);
    __syncthreads();                          // reads done before next overwrite
  }

  // ---- epilogue ----
  const int flagv = SCATTER ? flag[0] : 0;
  float bv2[4];
#pragma unroll
  for (int j = 0; j < 4; ++j)
    bv2[j] = biasF[(size_t)e * Nc + colStart + wn * 64 + j * 16 + fr];

  if (SCATTER && flagv) {
    // fp32-output path: exact scalar stores from acc (4-row x 64B chunks, line-dense)
#pragma unroll
    for (int i = 0; i < 4; ++i)
#pragma unroll
      for (int r = 0; r < 4; ++r) {
        const int gr = rowStart + wm * 64 + i * 16 + quad * 4 + r;
        const int crow = rowmap[gr];
        if (crow < 0) continue;
        const size_t cbase = (size_t)crow * Nc + colStart + wn * 64 + fr;
#pragma unroll
        for (int j = 0; j < 4; ++j)
          ((float*)C)[cbase + j * 16] = acc[i][j][r] + bv2[j];
      }
    return;
  }

  __syncthreads();
#pragma unroll
  for (int i = 0; i < 4; ++i)
#pragma unroll
    for (int r = 0; r < 4; ++r) {
      const int row = wm * 64 + i * 16 + quad * 4 + r;   // C/D: row=(lane>>4)*4+reg
#pragma unroll
      for (int j = 0; j < 4; ++j) {
        float v = acc[i][j][r] + bv2[j];
        if (RELU) v = fmaxf(v, 0.f);
        smem[row * CSTRIDE + wn * 64 + j * 16 + fr] = f2bf(v);
      }
    }
  __syncthreads();

#pragma unroll
  for (int it = 0; it < 8; ++it) {
    const int idx = it * 256 + tid;
    const int row = idx >> 4, c16 = idx & 15;
    int crow;
    if (SCATTER) {
      crow = rowmap[rowStart + row];
      if (crow < 0) continue;                 // padding row
    } else {
      crow = rowStart + row - rowBase;        // segment-local
    }
    const uint4 vv = *(const uint4*)&smem[row * CSTRIDE + c16 * 8];
    *(uint4*)&((unsigned short*)C)[(size_t)crow * Nc + colStart + c16 * 8] = vv;
  }
}

extern "C" void kernel_launch(void* const* d_in, const int* in_sizes, int n_in,
                              void* d_out, int out_size, void* d_ws, size_t ws_size,
                              hipStream_t stream) {
  const void* x  = d_in[0];
  const void* Wg = d_in[1];
  const void* bg = d_in[2];
  const void* W0 = d_in[3];
  const void* b0 = d_in[4];
  const void* W1 = d_in[5];
  const void* b1 = d_in[6];
  const void* W2 = d_in[7];
  const void* b2 = d_in[8];

  char* ws = (char*)d_ws;
  // fixed workspace layout (~101.3 MB) + wgF + adaptive h0/h1
  unsigned short* WT0 = (unsigned short*)(ws + 0);            //  8 MB [E][DH][DIN]
  unsigned short* WT1 = (unsigned short*)(ws + 8388608);      // 16 MB [E][DH][DH]
  unsigned short* WT2 = (unsigned short*)(ws + 25165824);     //  8 MB [E][DOUT][DH]
  unsigned short* xc  = (unsigned short*)(ws + 33554432);     // 64 MB [N][DIN] bf16 (flag=1 only)
  float* bf0 = (float*)(ws + 100663296);
  float* bf1 = (float*)(ws + 100696064);
  float* bf2 = (float*)(ws + 100728832);
  int* rowmap = (int*)(ws + 100745216);                       // MP_CAP ints
  int* eidx   = (int*)(ws + 101011456);                       // N ints
  int* counts = (int*)(ws + 101273600);
  int* off    = (int*)(ws + 101273664);
  int* fill   = (int*)(ws + 101273728);
  int* flag   = (int*)(ws + 101273792);
  float* wgF  = (float*)(ws + 101274624);                     // 16 KB [8][512] f32
  const size_t FIXED = 101291008;
  unsigned short* h0 = (unsigned short*)(ws + FIXED);

  // segment sizing: h0+h1 = segBlocks * 524288 B; prefer multiples of 8 for the swizzle
  int segBlocks = 1;
  if (ws_size > FIXED + 524288) {
    size_t sb = (ws_size - FIXED) / 524288;
    segBlocks = (sb > ROW_BLOCKS) ? ROW_BLOCKS : (int)sb;
    if (segBlocks >= 8) segBlocks &= ~7;
  }
  unsigned short* h1 = h0 + (size_t)segBlocks * 128 * DH;
  const int nseg = (ROW_BLOCKS + segBlocks - 1) / segBlocks;

  detect_k<<<1, 256, 0, stream>>>((const unsigned short*)x, flag, counts, fill);

  prep_k<<<161, 256, 0, stream>>>(b0, b1, b2, bf0, bf1, bf2, rowmap, Wg, wgF, flag);

  transpose_all_k<<<4096, 1024, 0, stream>>>(W0, W1, W2, WT0, WT1, WT2, flag);

  gating_k<<<N_TOK / 4, 256, 0, stream>>>(x, wgF, bg, xc, eidx, counts, flag);

  scatter_k<<<N_TOK / 256, 256, 0, stream>>>(eidx, counts, off, fill, rowmap);

  for (int s = 0; s < nseg; ++s) {
    const int rowBase = s * segBlocks * 128;
    // layer 0: gather x rows -> h0 (relu); ncb = DH/128 = 8
    gemm_k<1, 1, 0><<<dim3(8 * segBlocks), 256, 0, stream>>>(
        (const unsigned short*)x, xc, WT0, bf0, h0, rowmap, off, flag, DIN, DH, rowBase, 8, 3);
    // layer 1: h0 -> h1 (relu); ncb = 8
    gemm_k<0, 1, 0><<<dim3(8 * segBlocks), 256, 0, stream>>>(
        h0, h0, WT1, bf1, h1, rowmap, off, flag, DH, DH, rowBase, 8, 3);
    // layer 2: h1 -> out (scatter, bias only); ncb = DOUT/128 = 4
    gemm_k<0, 0, 1><<<dim3(4 * segBlocks), 256, 0, stream>>>(
        h1, h1, WT2, bf2, d_out, rowmap, off, flag, DH, DOUT, rowBase, 4, 2);
  }
}

// Round 6
// 913.191 us; speedup vs baseline: 1.0056x; 1.0043x over previous
//
#include <hip/hip_runtime.h>
#include <stdint.h>

// Problem constants
#define N_TOK 65536
#define DIN   512
#define DH    1024
#define DOUT  512
#define NE    8
#define MP_CAP 66560     // padded row space capacity (N + 8*128, /128)
#define ROW_BLOCKS 520   // MP_CAP / 128
#define CSTRIDE 144      // epilogue C-stage LDS row stride (ushorts): bank-conflict-free

typedef __bf16 bf16x8 __attribute__((ext_vector_type(8)));
typedef float  f32x4  __attribute__((ext_vector_type(4)));

// address-space-qualified pointer types for global_load_lds
typedef __attribute__((address_space(3))) void  lds_void;
typedef const __attribute__((address_space(1))) void g_void;

__device__ __forceinline__ float bf2f(unsigned short u) {
  union { unsigned int i; float f; } v; v.i = ((unsigned int)u) << 16; return v.f;
}
__device__ __forceinline__ unsigned short f2bf(float f) {
  unsigned int u = __builtin_bit_cast(unsigned int, f);
  u += 0x7fffu + ((u >> 16) & 1u);      // RNE
  return (unsigned short)(u >> 16);
}

// ---------------- dtype probe + zero counts/fill (fp32-read-as-ushort has wild exps) --------
__global__ void detect_k(const unsigned short* __restrict__ x, int* __restrict__ flag,
                         int* __restrict__ counts, int* __restrict__ fill) {
  __shared__ int cnt;
  if (threadIdx.x < 8) { counts[threadIdx.x] = 0; fill[threadIdx.x] = 0; }
  if (threadIdx.x == 0) cnt = 0;
  __syncthreads();
  int c = 0;
  for (int i = threadIdx.x; i < 16384; i += 256) {
    const unsigned short u = x[2 * i];
    const int ex = (u >> 7) & 0xFF;
    if (ex > 140) ++c;
  }
  atomicAdd(&cnt, c);
  __syncthreads();
  if (threadIdx.x == 0) flag[0] = (cnt > 512) ? 1 : 0;   // 1 = inputs are fp32
}

// ------- prep: biases -> fp32, rowmap = -1 fill, Wg -> wgF[e][k] f32 (transposed) -------
__global__ __launch_bounds__(256)
void prep_k(const void* __restrict__ b0, const void* __restrict__ b1,
            const void* __restrict__ b2, float* __restrict__ bf0,
            float* __restrict__ bf1, float* __restrict__ bf2,
            int* __restrict__ rowmap, const void* __restrict__ Wg,
            float* __restrict__ wgF, const int* __restrict__ flag) {
  const int b = blockIdx.x;
  if (b < 65) {                       // rowmap: 66560 ints = 65 blocks * 256 * int4
    const int i = (b * 256 + threadIdx.x) * 4;
    *(int4*)&rowmap[i] = (int4){-1, -1, -1, -1};
    return;
  }
  const int fv = flag[0];
  if (b < 145) {                      // biases: 20480 elements
    const int i = (b - 65) * 256 + threadIdx.x;
    const void* src; float* dst; int li;
    if (i < NE * DH) { src = b0; dst = bf0; li = i; }
    else if (i < 2 * NE * DH) { src = b1; dst = bf1; li = i - NE * DH; }
    else { src = b2; dst = bf2; li = i - 2 * NE * DH; }
    dst[li] = fv ? ((const float*)src)[li] : bf2f(((const unsigned short*)src)[li]);
    return;
  }
  // wgF[e][k] = Wg[k][e], f32: 4096 elements in 16 blocks
  const int idx = (b - 145) * 256 + threadIdx.x;
  const int e = idx >> 9, k = idx & 511;
  wgF[idx] = fv ? ((const float*)Wg)[k * 8 + e]
                : bf2f(((const unsigned short*)Wg)[k * 8 + e]);
}

// ---------------- all three weight transposes in one launch ----------------
// W[e][K][Nn] -> WT[e][Nn][K] (bf16 out); tile decode from 1-D grid.
__global__ __launch_bounds__(1024)
void transpose_all_k(const void* __restrict__ W0, const void* __restrict__ W1,
                     const void* __restrict__ W2, unsigned short* __restrict__ WT0,
                     unsigned short* __restrict__ WT1, unsigned short* __restrict__ WT2,
                     const int* __restrict__ flag) {
  __shared__ unsigned short tile[64][65];
  const int fv = flag[0];
  int b = blockIdx.x;
  const void* W; unsigned short* WT; int K, Nn, e, n0, k0;
  if (b < 1024) {            // W0: per-expert 16 n-tiles x 8 k-tiles
    W = W0; WT = WT0; K = DIN; Nn = DH;
    e = b >> 7; const int r = b & 127; n0 = (r & 15) * 64; k0 = (r >> 4) * 64;
  } else if (b < 3072) {     // W1: 16 x 16
    b -= 1024; W = W1; WT = WT1; K = DH; Nn = DH;
    e = b >> 8; const int r = b & 255; n0 = (r & 15) * 64; k0 = (r >> 4) * 64;
  } else {                   // W2: 8 n-tiles x 16 k-tiles
    b -= 3072; W = W2; WT = WT2; K = DH; Nn = DOUT;
    e = b >> 7; const int r = b & 127; n0 = (r & 7) * 64; k0 = (r >> 3) * 64;
  }
  const size_t base = (size_t)e * K * Nn;
  unsigned short* dst = WT + base;
  const int tx = threadIdx.x & 63, ty = threadIdx.x >> 6;
#pragma unroll
  for (int i = 0; i < 4; ++i) {
    const size_t idx = base + (size_t)(k0 + ty + i * 16) * Nn + n0 + tx;
    tile[ty + i * 16][tx] = fv ? f2bf(((const float*)W)[idx])
                               : ((const unsigned short*)W)[idx];
  }
  __syncthreads();
#pragma unroll
  for (int i = 0; i < 4; ++i)
    dst[(size_t)(n0 + ty + i * 16) * K + k0 + tx] = tile[tx][ty + i * 16];
}

// ---------------- fused gating: logits(fp64) + argmax + xc(bf16) + counts ----------------
// One wave per token, k = lane*8 + j: x is 2 float4 loads/lane, each expert's wgF slice
// is 2 float4 loads/lane -> 18 independent vector loads the compiler can batch (the old
// k = i*64+lane layout serialized ~72 scalar loads at full latency; 212 us, VALU 15%,
// HBM 8% = latency-bound). fp64 accumulation (order change is f64-noise, ~1e-16 vs
// logit gaps ~1e-1), same 6-level shfl_down tree + strict-> argmax (np.argmax first-max).
// xc bf16 canonical copy fused as one packed uint4 store per lane.
__global__ __launch_bounds__(256)
void gating_k(const void* __restrict__ x, const float* __restrict__ wgF,
              const void* __restrict__ bg, unsigned short* __restrict__ xc,
              int* __restrict__ eidx, int* __restrict__ counts,
              const int* __restrict__ flag) {
  __shared__ int hist[8];
  const int tid = threadIdx.x;
  if (tid < 8) hist[tid] = 0;
  __syncthreads();

  const int wv = tid >> 6, lane = tid & 63;
  const int t = blockIdx.x * 4 + wv;
  const int fv = flag[0];
  const int k0 = lane * 8;

  float xv[8];
  if (fv) {
    const float* xr = (const float*)x + (size_t)t * DIN + k0;
    const f32x4 a = *(const f32x4*)xr;
    const f32x4 b = *(const f32x4*)(xr + 4);
#pragma unroll
    for (int j = 0; j < 4; ++j) { xv[j] = a[j]; xv[4 + j] = b[j]; }
    unsigned short o[8];
#pragma unroll
    for (int j = 0; j < 8; ++j) o[j] = f2bf(xv[j]);
    *(uint4*)&xc[(size_t)t * DIN + k0] = *(const uint4*)o;   // fused canonical copy
  } else {
    const unsigned short* xr = (const unsigned short*)x + (size_t)t * DIN + k0;
    const uint4 u = *(const uint4*)xr;
    const unsigned int uw[4] = {u.x, u.y, u.z, u.w};
#pragma unroll
    for (int j = 0; j < 4; ++j) {
      xv[2 * j]     = bf2f((unsigned short)(uw[j] & 0xffff));
      xv[2 * j + 1] = bf2f((unsigned short)(uw[j] >> 16));
    }
  }

  double acc[8];
#pragma unroll
  for (int e = 0; e < 8; ++e) {
    const f32x4 wa = *(const f32x4*)&wgF[e * DIN + k0];
    const f32x4 wb = *(const f32x4*)&wgF[e * DIN + k0 + 4];
    double s = 0.0;
#pragma unroll
    for (int j = 0; j < 4; ++j) s += (double)xv[j] * (double)wa[j];
#pragma unroll
    for (int j = 0; j < 4; ++j) s += (double)xv[4 + j] * (double)wb[j];
    acc[e] = s;
  }

#pragma unroll
  for (int o = 32; o > 0; o >>= 1)
#pragma unroll
    for (int e = 0; e < 8; ++e) acc[e] += __shfl_down(acc[e], o, 64);
  if (lane == 0) {
    int bi = 0;
    double best = acc[0] + (double)(fv ? ((const float*)bg)[0]
                                       : bf2f(((const unsigned short*)bg)[0]));
#pragma unroll
    for (int e = 1; e < 8; ++e) {
      const double v = acc[e] + (double)(fv ? ((const float*)bg)[e]
                                            : bf2f(((const unsigned short*)bg)[e]));
      if (v > best) { best = v; bi = e; }   // strict >: first-max wins (np.argmax)
    }
    eidx[t] = bi;
    atomicAdd(&hist[bi], 1);
  }
  __syncthreads();
  if (tid < 8 && hist[tid]) atomicAdd(&counts[tid], hist[tid]);
}

// ---------------- scatter tokens into rowmap (local prefix from counts) ----------------
__global__ __launch_bounds__(256)
void scatter_k(const int* __restrict__ eidx, const int* __restrict__ counts,
               int* __restrict__ off_g, int* __restrict__ fill,
               int* __restrict__ rowmap) {
  int off[8];
  {
    int a = 0;
#pragma unroll
    for (int e2 = 0; e2 < 8; ++e2) { off[e2] = a; a += (counts[e2] + 127) & ~127; }
    if (blockIdx.x == 0 && threadIdx.x == 0) {
      off_g[0] = 0;
      int aa = 0;
#pragma unroll
      for (int e2 = 0; e2 < 8; ++e2) { aa += (counts[e2] + 127) & ~127; off_g[e2 + 1] = aa; }
    }
  }
  const int t = blockIdx.x * 256 + threadIdx.x;
  const int lane = threadIdx.x & 63;
  const int e = eidx[t];
#pragma unroll
  for (int ex = 0; ex < 8; ++ex) {
    unsigned long long m = __ballot(e == ex);
    if (e == ex) {
      const unsigned long long lt = (1ULL << lane) - 1ULL;
      const int rank = __popcll(m & lt);
      const int leader = __ffsll((unsigned long long)m) - 1;
      int base = 0;
      if (lane == leader) base = atomicAdd(&fill[ex], (int)__popcll(m));
      base = __shfl(base, leader, 64);
      rowmap[off[ex] + base + rank] = t;
    }
  }
}

// ---------------- grouped GEMM: C[128 x 128] per block, K-step 64 ----------------
// (unchanged — global_load_lds width=16, Rule-21 swizzle)
template <int GATHER, int RELU, int SCATTER>
__global__ __launch_bounds__(256, 2)
void gemm_k(const unsigned short* __restrict__ A, const unsigned short* __restrict__ Axc,
            const unsigned short* __restrict__ BT,
            const float* __restrict__ biasF, void* __restrict__ C,
            const int* __restrict__ rowmap, const int* __restrict__ off,
            const int* __restrict__ flag, const int K, const int Nc, const int rowBase,
            const int ncb, const int lncb) {
  __shared__ __align__(16) unsigned short smem[128 * CSTRIDE];  // 36 KB
  unsigned short* As = smem;                 // staging: 128x64 = 16 KB
  unsigned short* Bs = smem + 128 * 64;      // staging: 128x64 = 16 KB

  // ---- swizzled block -> (rowg, col) ----
  const int segBlocksLocal = gridDim.x >> lncb;
  const int fullRows = segBlocksLocal & ~7;
  const int fullBlocks = fullRows << lncb;
  int col, rowg;
  {
    const int p = blockIdx.x;
    if (p < fullBlocks) {
      const int xcd = p & 7, qq = p >> 3;
      col = qq & (ncb - 1);
      rowg = ((qq >> lncb) << 3) + xcd;
    } else {
      const int r = p - fullBlocks;
      col = r & (ncb - 1);
      rowg = fullRows + (r >> lncb);
    }
  }

  const int Mp = off[8];
  const int rowStart = rowBase + rowg * 128;
  if (rowStart >= Mp) return;
  int e = 0;
#pragma unroll
  for (int j = 1; j <= 8; ++j) e += (off[j] <= rowStart) ? 1 : 0;

  const int colStart = col * 128;
  const int tid = threadIdx.x;
  const int w = tid >> 6, lane = tid & 63;
  const int subrow = lane >> 3;
  const int q = lane & 7;
  const int slot = q ^ subrow;               // inverse-swizzled global chunk index

  const unsigned short* Ause = (GATHER && flag[0]) ? Axc : A;
  const unsigned short* Be = BT + (size_t)e * Nc * K;

  // per-lane global source pointers (chunk `slot`), wave-uniform LDS dest offsets
  const unsigned short* aptr[4];
  const unsigned short* bptr[4];
  int ldsOff[4];
#pragma unroll
  for (int i = 0; i < 4; ++i) {
    const int r = i * 32 + w * 8 + subrow;
    int arow;
    if (GATHER) {
      arow = rowmap[rowStart + r];
      if (arow < 0) arow = 0;                 // padding row: load safe garbage
    } else {
      arow = rowStart + r - rowBase;          // segment-local
    }
    aptr[i] = Ause + (size_t)arow * K + slot * 8;
    bptr[i] = Be + (size_t)(colStart + r) * K + slot * 8;
    ldsOff[i] = (i * 32 + w * 8) * 64;        // linear dest: 8 rows x 128 B per call
  }

  const int wm = w >> 1, wn = w & 1;
  const int fr = lane & 15, quad = lane >> 4;

  f32x4 acc[4][4];
#pragma unroll
  for (int i = 0; i < 4; ++i)
#pragma unroll
    for (int j = 0; j < 4; ++j) acc[i][j] = (f32x4){0.f, 0.f, 0.f, 0.f};

  int aoff[2][4], boff[2][4];
#pragma unroll
  for (int s = 0; s < 2; ++s)
#pragma unroll
    for (int i = 0; i < 4; ++i) {
      const int qq = quad + s * 4;
      const int rowA = wm * 64 + i * 16 + fr;
      aoff[s][i] = rowA * 64 + (qq ^ (rowA & 7)) * 8;
      const int rowB = wn * 64 + i * 16 + fr;
      boff[s][i] = rowB * 64 + (qq ^ (rowB & 7)) * 8;
    }

  for (int k0 = 0; k0 < K; k0 += 64) {
    // async global -> LDS staging (this K-step's tile). Prior iteration's trailing
    // barrier guarantees all LDS reads of the previous tile completed.
#pragma unroll
    for (int i = 0; i < 4; ++i) {
      __builtin_amdgcn_global_load_lds((g_void*)(aptr[i] + k0),
                                       (lds_void*)(As + ldsOff[i]), 16, 0, 0);
      __builtin_amdgcn_global_load_lds((g_void*)(bptr[i] + k0),
                                       (lds_void*)(Bs + ldsOff[i]), 16, 0, 0);
    }
    __syncthreads();                          // vmcnt(0) drain -> tile visible to all
    bf16x8 af[2][4], bfv[2][4];
#pragma unroll
    for (int s = 0; s < 2; ++s)
#pragma unroll
      for (int i = 0; i < 4; ++i) {
        af[s][i] = *(const bf16x8*)&As[aoff[s][i]];
        bfv[s][i] = *(const bf16x8*)&Bs[boff[s][i]];
      }
#pragma unroll
    for (int s = 0; s < 2; ++s)
#pragma unroll
      for (int i = 0; i < 4; ++i)
#pragma unroll
        for (int j = 0; j < 4; ++j)
          acc[i][j] = __builtin_amdgcn_mfma_f32_16x16x32_bf16(af[s][i], bfv[s][j],
                                                              acc[i][j], 0, 0, 0);
    __syncthreads();                          // reads done before next overwrite
  }

  // ---- epilogue ----
  const int flagv = SCATTER ? flag[0] : 0;
  float bv2[4];
#pragma unroll
  for (int j = 0; j < 4; ++j)
    bv2[j] = biasF[(size_t)e * Nc + colStart + wn * 64 + j * 16 + fr];

  if (SCATTER && flagv) {
    // fp32-output path: exact scalar stores from acc (4-row x 64B chunks, line-dense)
#pragma unroll
    for (int i = 0; i < 4; ++i)
#pragma unroll
      for (int r = 0; r < 4; ++r) {
        const int gr = rowStart + wm * 64 + i * 16 + quad * 4 + r;
        const int crow = rowmap[gr];
        if (crow < 0) continue;
        const size_t cbase = (size_t)crow * Nc + colStart + wn * 64 + fr;
#pragma unroll
        for (int j = 0; j < 4; ++j)
          ((float*)C)[cbase + j * 16] = acc[i][j][r] + bv2[j];
      }
    return;
  }

  __syncthreads();
#pragma unroll
  for (int i = 0; i < 4; ++i)
#pragma unroll
    for (int r = 0; r < 4; ++r) {
      const int row = wm * 64 + i * 16 + quad * 4 + r;   // C/D: row=(lane>>4)*4+reg
#pragma unroll
      for (int j = 0; j < 4; ++j) {
        float v = acc[i][j][r] + bv2[j];
        if (RELU) v = fmaxf(v, 0.f);
        smem[row * CSTRIDE + wn * 64 + j * 16 + fr] = f2bf(v);
      }
    }
  __syncthreads();

#pragma unroll
  for (int it = 0; it < 8; ++it) {
    const int idx = it * 256 + tid;
    const int row = idx >> 4, c16 = idx & 15;
    int crow;
    if (SCATTER) {
      crow = rowmap[rowStart + row];
      if (crow < 0) continue;                 // padding row
    } else {
      crow = rowStart + row - rowBase;        // segment-local
    }
    const uint4 vv = *(const uint4*)&smem[row * CSTRIDE + c16 * 8];
    *(uint4*)&((unsigned short*)C)[(size_t)crow * Nc + colStart + c16 * 8] = vv;
  }
}

extern "C" void kernel_launch(void* const* d_in, const int* in_sizes, int n_in,
                              void* d_out, int out_size, void* d_ws, size_t ws_size,
                              hipStream_t stream) {
  const void* x  = d_in[0];
  const void* Wg = d_in[1];
  const void* bg = d_in[2];
  const void* W0 = d_in[3];
  const void* b0 = d_in[4];
  const void* W1 = d_in[5];
  const void* b1 = d_in[6];
  const void* W2 = d_in[7];
  const void* b2 = d_in[8];

  char* ws = (char*)d_ws;
  // fixed workspace layout (~101.3 MB) + wgF + adaptive h0/h1
  unsigned short* WT0 = (unsigned short*)(ws + 0);            //  8 MB [E][DH][DIN]
  unsigned short* WT1 = (unsigned short*)(ws + 8388608);      // 16 MB [E][DH][DH]
  unsigned short* WT2 = (unsigned short*)(ws + 25165824);     //  8 MB [E][DOUT][DH]
  unsigned short* xc  = (unsigned short*)(ws + 33554432);     // 64 MB [N][DIN] bf16 (flag=1 only)
  float* bf0 = (float*)(ws + 100663296);
  float* bf1 = (float*)(ws + 100696064);
  float* bf2 = (float*)(ws + 100728832);
  int* rowmap = (int*)(ws + 100745216);                       // MP_CAP ints
  int* eidx   = (int*)(ws + 101011456);                       // N ints
  int* counts = (int*)(ws + 101273600);
  int* off    = (int*)(ws + 101273664);
  int* fill   = (int*)(ws + 101273728);
  int* flag   = (int*)(ws + 101273792);
  float* wgF  = (float*)(ws + 101274624);                     // 16 KB [8][512] f32
  const size_t FIXED = 101291008;
  unsigned short* h0 = (unsigned short*)(ws + FIXED);

  // segment sizing: h0+h1 = segBlocks * 524288 B; prefer multiples of 8 for the swizzle
  int segBlocks = 1;
  if (ws_size > FIXED + 524288) {
    size_t sb = (ws_size - FIXED) / 524288;
    segBlocks = (sb > ROW_BLOCKS) ? ROW_BLOCKS : (int)sb;
    if (segBlocks >= 8) segBlocks &= ~7;
  }
  unsigned short* h1 = h0 + (size_t)segBlocks * 128 * DH;
  const int nseg = (ROW_BLOCKS + segBlocks - 1) / segBlocks;

  detect_k<<<1, 256, 0, stream>>>((const unsigned short*)x, flag, counts, fill);

  prep_k<<<161, 256, 0, stream>>>(b0, b1, b2, bf0, bf1, bf2, rowmap, Wg, wgF, flag);

  transpose_all_k<<<4096, 1024, 0, stream>>>(W0, W1, W2, WT0, WT1, WT2, flag);

  gating_k<<<N_TOK / 4, 256, 0, stream>>>(x, wgF, bg, xc, eidx, counts, flag);

  scatter_k<<<N_TOK / 256, 256, 0, stream>>>(eidx, counts, off, fill, rowmap);

  for (int s = 0; s < nseg; ++s) {
    const int rowBase = s * segBlocks * 128;
    // layer 0: gather x rows -> h0 (relu); ncb = DH/128 = 8
    gemm_k<1, 1, 0><<<dim3(8 * segBlocks), 256, 0, stream>>>(
        (const unsigned short*)x, xc, WT0, bf0, h0, rowmap, off, flag, DIN, DH, rowBase, 8, 3);
    // layer 1: h0 -> h1 (relu); ncb = 8
    gemm_k<0, 1, 0><<<dim3(8 * segBlocks), 256, 0, stream>>>(
        h0, h0, WT1, bf1, h1, rowmap, off, flag, DH, DH, rowBase, 8, 3);
    // layer 2: h1 -> out (scatter, bias only); ncb = DOUT/128 = 4
    gemm_k<0, 0, 1><<<dim3(4 * segBlocks), 256, 0, stream>>>(
        h1, h1, WT2, bf2, d_out, rowmap, off, flag, DH, DOUT, rowBase, 4, 2);
  }
}

// Round 7
// 886.667 us; speedup vs baseline: 1.0357x; 1.0299x over previous
//
#include <hip/hip_runtime.h>
#include <stdint.h>

// Problem constants
#define N_TOK 65536
#define DIN   512
#define DH    1024
#define DOUT  512
#define NE    8
#define MP_CAP 66560     // padded row space capacity (N + 8*128, /128)
#define ROW_BLOCKS 520   // MP_CAP / 128
#define CSTRIDE 144      // epilogue C-stage LDS row stride (ushorts): bank-conflict-free

typedef __bf16 bf16x8 __attribute__((ext_vector_type(8)));
typedef float  f32x4  __attribute__((ext_vector_type(4)));

// address-space-qualified pointer types for global_load_lds
typedef __attribute__((address_space(3))) void  lds_void;
typedef const __attribute__((address_space(1))) void g_void;

__device__ __forceinline__ float bf2f(unsigned short u) {
  union { unsigned int i; float f; } v; v.i = ((unsigned int)u) << 16; return v.f;
}
__device__ __forceinline__ unsigned short f2bf(float f) {
  unsigned int u = __builtin_bit_cast(unsigned int, f);
  u += 0x7fffu + ((u >> 16) & 1u);      // RNE
  return (unsigned short)(u >> 16);
}

// ---------------- dtype probe + zero counts/fill (fp32-read-as-ushort has wild exps) --------
__global__ void detect_k(const unsigned short* __restrict__ x, int* __restrict__ flag,
                         int* __restrict__ counts, int* __restrict__ fill) {
  __shared__ int cnt;
  if (threadIdx.x < 8) { counts[threadIdx.x] = 0; fill[threadIdx.x] = 0; }
  if (threadIdx.x == 0) cnt = 0;
  __syncthreads();
  int c = 0;
  for (int i = threadIdx.x; i < 16384; i += 256) {
    const unsigned short u = x[2 * i];
    const int ex = (u >> 7) & 0xFF;
    if (ex > 140) ++c;
  }
  atomicAdd(&cnt, c);
  __syncthreads();
  if (threadIdx.x == 0) flag[0] = (cnt > 512) ? 1 : 0;   // 1 = inputs are fp32
}

// ------- prep: biases -> fp32, rowmap = -1 fill, Wg -> wgF[e][k] f32 (transposed) -------
__global__ __launch_bounds__(256)
void prep_k(const void* __restrict__ b0, const void* __restrict__ b1,
            const void* __restrict__ b2, float* __restrict__ bf0,
            float* __restrict__ bf1, float* __restrict__ bf2,
            int* __restrict__ rowmap, const void* __restrict__ Wg,
            float* __restrict__ wgF, const int* __restrict__ flag) {
  const int b = blockIdx.x;
  if (b < 65) {                       // rowmap: 66560 ints = 65 blocks * 256 * int4
    const int i = (b * 256 + threadIdx.x) * 4;
    *(int4*)&rowmap[i] = (int4){-1, -1, -1, -1};
    return;
  }
  const int fv = flag[0];
  if (b < 145) {                      // biases: 20480 elements
    const int i = (b - 65) * 256 + threadIdx.x;
    const void* src; float* dst; int li;
    if (i < NE * DH) { src = b0; dst = bf0; li = i; }
    else if (i < 2 * NE * DH) { src = b1; dst = bf1; li = i - NE * DH; }
    else { src = b2; dst = bf2; li = i - 2 * NE * DH; }
    dst[li] = fv ? ((const float*)src)[li] : bf2f(((const unsigned short*)src)[li]);
    return;
  }
  // wgF[e][k] = Wg[k][e], f32: 4096 elements in 16 blocks
  const int idx = (b - 145) * 256 + threadIdx.x;
  const int e = idx >> 9, k = idx & 511;
  wgF[idx] = fv ? ((const float*)Wg)[k * 8 + e]
                : bf2f(((const unsigned short*)Wg)[k * 8 + e]);
}

// ---------------- all three weight transposes in one launch ----------------
// W[e][K][Nn] -> WT[e][Nn][K] (bf16 out); tile decode from 1-D grid.
__global__ __launch_bounds__(1024)
void transpose_all_k(const void* __restrict__ W0, const void* __restrict__ W1,
                     const void* __restrict__ W2, unsigned short* __restrict__ WT0,
                     unsigned short* __restrict__ WT1, unsigned short* __restrict__ WT2,
                     const int* __restrict__ flag) {
  __shared__ unsigned short tile[64][65];
  const int fv = flag[0];
  int b = blockIdx.x;
  const void* W; unsigned short* WT; int K, Nn, e, n0, k0;
  if (b < 1024) {            // W0: per-expert 16 n-tiles x 8 k-tiles
    W = W0; WT = WT0; K = DIN; Nn = DH;
    e = b >> 7; const int r = b & 127; n0 = (r & 15) * 64; k0 = (r >> 4) * 64;
  } else if (b < 3072) {     // W1: 16 x 16
    b -= 1024; W = W1; WT = WT1; K = DH; Nn = DH;
    e = b >> 8; const int r = b & 255; n0 = (r & 15) * 64; k0 = (r >> 4) * 64;
  } else {                   // W2: 8 n-tiles x 16 k-tiles
    b -= 3072; W = W2; WT = WT2; K = DH; Nn = DOUT;
    e = b >> 7; const int r = b & 127; n0 = (r & 7) * 64; k0 = (r >> 3) * 64;
  }
  const size_t base = (size_t)e * K * Nn;
  unsigned short* dst = WT + base;
  const int tx = threadIdx.x & 63, ty = threadIdx.x >> 6;
#pragma unroll
  for (int i = 0; i < 4; ++i) {
    const size_t idx = base + (size_t)(k0 + ty + i * 16) * Nn + n0 + tx;
    tile[ty + i * 16][tx] = fv ? f2bf(((const float*)W)[idx])
                               : ((const unsigned short*)W)[idx];
  }
  __syncthreads();
#pragma unroll
  for (int i = 0; i < 4; ++i)
    dst[(size_t)(n0 + ty + i * 16) * K + k0 + tx] = tile[tx][ty + i * 16];
}

// ---------------- fused gating: logits(fp64) + argmax + xc(bf16) + counts ----------------
// Lane = (token, expert): each wave owns 8 tokens x 8 experts; lane (tok,e) computes the
// ENTIRE 512-length dot serially (128 f32x4 steps, 4 independent fp64 partials) — no
// cross-lane reduce until a 3-level butterfly within the 8-lane expert group (6 bpermutes
// vs the old wave-wide tree's 96: that serial ~12K-cycle chain was round-6's 202 us).
// x reads: 8-lane broadcast over 8 row-streams, each 128B line fully used across 8
// consecutive iterations (L1-resident). wgF: 16 KB L1-hot, 8-way broadcast.
// Argmax butterfly = (max value, min expert index): associative, == np.argmax first-max.
__global__ __launch_bounds__(256)
void gating_k(const void* __restrict__ x, const float* __restrict__ wgF,
              const void* __restrict__ bg, unsigned short* __restrict__ xc,
              int* __restrict__ eidx, int* __restrict__ counts,
              const int* __restrict__ flag) {
  __shared__ int hist[8];
  const int tid = threadIdx.x;
  if (tid < 8) hist[tid] = 0;
  __syncthreads();

  const int wv = tid >> 6, lane = tid & 63;
  const int tok0 = (blockIdx.x * 4 + wv) * 8;      // 8 tokens per wave
  const int fv = flag[0];
  const int tok = lane >> 3, e = lane & 7;
  const float* wrow = wgF + e * DIN;

  double s0 = 0.0, s1 = 0.0, s2 = 0.0, s3 = 0.0;

  if (fv) {
    // fused canonical bf16 copy of this wave's 8 rows (coalesced; 2nd x read hits L2/L3)
    const float* xf = (const float*)x + (size_t)tok0 * DIN;
    unsigned short* xo = xc + (size_t)tok0 * DIN;
#pragma unroll
    for (int j = 0; j < 16; ++j) {
      const int f = j * 64 + lane;
      const int row = f >> 7, c4 = (f & 127) * 4;
      const f32x4 v = *(const f32x4*)&xf[row * DIN + c4];
      unsigned short o[4] = {f2bf(v[0]), f2bf(v[1]), f2bf(v[2]), f2bf(v[3])};
      *(uint2*)&xo[row * DIN + c4] = *(const uint2*)o;
    }
    const float* xr = (const float*)x + (size_t)(tok0 + tok) * DIN;
#pragma unroll 8
    for (int k4 = 0; k4 < 128; ++k4) {
      const f32x4 xv = *(const f32x4*)&xr[k4 * 4];
      const f32x4 wv2 = *(const f32x4*)&wrow[k4 * 4];
      s0 += (double)xv[0] * (double)wv2[0];
      s1 += (double)xv[1] * (double)wv2[1];
      s2 += (double)xv[2] * (double)wv2[2];
      s3 += (double)xv[3] * (double)wv2[3];
    }
  } else {
    const unsigned short* xr = (const unsigned short*)x + (size_t)(tok0 + tok) * DIN;
#pragma unroll 4
    for (int k8 = 0; k8 < 64; ++k8) {
      const uint4 u = *(const uint4*)&xr[k8 * 8];
      const f32x4 wa = *(const f32x4*)&wrow[k8 * 8];
      const f32x4 wb = *(const f32x4*)&wrow[k8 * 8 + 4];
      const unsigned int uw[4] = {u.x, u.y, u.z, u.w};
      s0 += (double)bf2f((unsigned short)(uw[0] & 0xffff)) * (double)wa[0];
      s1 += (double)bf2f((unsigned short)(uw[0] >> 16))    * (double)wa[1];
      s2 += (double)bf2f((unsigned short)(uw[1] & 0xffff)) * (double)wa[2];
      s3 += (double)bf2f((unsigned short)(uw[1] >> 16))    * (double)wa[3];
      s0 += (double)bf2f((unsigned short)(uw[2] & 0xffff)) * (double)wb[0];
      s1 += (double)bf2f((unsigned short)(uw[2] >> 16))    * (double)wb[1];
      s2 += (double)bf2f((unsigned short)(uw[3] & 0xffff)) * (double)wb[2];
      s3 += (double)bf2f((unsigned short)(uw[3] >> 16))    * (double)wb[3];
    }
  }

  double v = (s0 + s1) + (s2 + s3);
  v += fv ? (double)((const float*)bg)[e]
          : (double)bf2f(((const unsigned short*)bg)[e]);
  int be = e;
#pragma unroll
  for (int d = 1; d <= 4; d <<= 1) {                 // within the 8-lane expert group
    const double vo = __shfl_xor(v, d, 64);
    const int eo = __shfl_xor(be, d, 64);
    if (vo > v || (vo == v && eo < be)) { v = vo; be = eo; }
  }
  if (e == 0) {                                      // one lane per token
    eidx[tok0 + tok] = be;
    atomicAdd(&hist[be], 1);
  }
  __syncthreads();
  if (tid < 8 && hist[tid]) atomicAdd(&counts[tid], hist[tid]);
}

// ---------------- scatter tokens into rowmap (local prefix from counts) ----------------
__global__ __launch_bounds__(256)
void scatter_k(const int* __restrict__ eidx, const int* __restrict__ counts,
               int* __restrict__ off_g, int* __restrict__ fill,
               int* __restrict__ rowmap) {
  int off[8];
  {
    int a = 0;
#pragma unroll
    for (int e2 = 0; e2 < 8; ++e2) { off[e2] = a; a += (counts[e2] + 127) & ~127; }
    if (blockIdx.x == 0 && threadIdx.x == 0) {
      off_g[0] = 0;
      int aa = 0;
#pragma unroll
      for (int e2 = 0; e2 < 8; ++e2) { aa += (counts[e2] + 127) & ~127; off_g[e2 + 1] = aa; }
    }
  }
  const int t = blockIdx.x * 256 + threadIdx.x;
  const int lane = threadIdx.x & 63;
  const int e = eidx[t];
#pragma unroll
  for (int ex = 0; ex < 8; ++ex) {
    unsigned long long m = __ballot(e == ex);
    if (e == ex) {
      const unsigned long long lt = (1ULL << lane) - 1ULL;
      const int rank = __popcll(m & lt);
      const int leader = __ffsll((unsigned long long)m) - 1;
      int base = 0;
      if (lane == leader) base = atomicAdd(&fill[ex], (int)__popcll(m));
      base = __shfl(base, leader, 64);
      rowmap[off[ex] + base + rank] = t;
    }
  }
}

// ---------------- grouped GEMM: C[128 x 128] per block, K-step 64 ----------------
// (unchanged — global_load_lds width=16, Rule-21 swizzle)
template <int GATHER, int RELU, int SCATTER>
__global__ __launch_bounds__(256, 2)
void gemm_k(const unsigned short* __restrict__ A, const unsigned short* __restrict__ Axc,
            const unsigned short* __restrict__ BT,
            const float* __restrict__ biasF, void* __restrict__ C,
            const int* __restrict__ rowmap, const int* __restrict__ off,
            const int* __restrict__ flag, const int K, const int Nc, const int rowBase,
            const int ncb, const int lncb) {
  __shared__ __align__(16) unsigned short smem[128 * CSTRIDE];  // 36 KB
  unsigned short* As = smem;                 // staging: 128x64 = 16 KB
  unsigned short* Bs = smem + 128 * 64;      // staging: 128x64 = 16 KB

  // ---- swizzled block -> (rowg, col) ----
  const int segBlocksLocal = gridDim.x >> lncb;
  const int fullRows = segBlocksLocal & ~7;
  const int fullBlocks = fullRows << lncb;
  int col, rowg;
  {
    const int p = blockIdx.x;
    if (p < fullBlocks) {
      const int xcd = p & 7, qq = p >> 3;
      col = qq & (ncb - 1);
      rowg = ((qq >> lncb) << 3) + xcd;
    } else {
      const int r = p - fullBlocks;
      col = r & (ncb - 1);
      rowg = fullRows + (r >> lncb);
    }
  }

  const int Mp = off[8];
  const int rowStart = rowBase + rowg * 128;
  if (rowStart >= Mp) return;
  int e = 0;
#pragma unroll
  for (int j = 1; j <= 8; ++j) e += (off[j] <= rowStart) ? 1 : 0;

  const int colStart = col * 128;
  const int tid = threadIdx.x;
  const int w = tid >> 6, lane = tid & 63;
  const int subrow = lane >> 3;
  const int q = lane & 7;
  const int slot = q ^ subrow;               // inverse-swizzled global chunk index

  const unsigned short* Ause = (GATHER && flag[0]) ? Axc : A;
  const unsigned short* Be = BT + (size_t)e * Nc * K;

  // per-lane global source pointers (chunk `slot`), wave-uniform LDS dest offsets
  const unsigned short* aptr[4];
  const unsigned short* bptr[4];
  int ldsOff[4];
#pragma unroll
  for (int i = 0; i < 4; ++i) {
    const int r = i * 32 + w * 8 + subrow;
    int arow;
    if (GATHER) {
      arow = rowmap[rowStart + r];
      if (arow < 0) arow = 0;                 // padding row: load safe garbage
    } else {
      arow = rowStart + r - rowBase;          // segment-local
    }
    aptr[i] = Ause + (size_t)arow * K + slot * 8;
    bptr[i] = Be + (size_t)(colStart + r) * K + slot * 8;
    ldsOff[i] = (i * 32 + w * 8) * 64;        // linear dest: 8 rows x 128 B per call
  }

  const int wm = w >> 1, wn = w & 1;
  const int fr = lane & 15, quad = lane >> 4;

  f32x4 acc[4][4];
#pragma unroll
  for (int i = 0; i < 4; ++i)
#pragma unroll
    for (int j = 0; j < 4; ++j) acc[i][j] = (f32x4){0.f, 0.f, 0.f, 0.f};

  int aoff[2][4], boff[2][4];
#pragma unroll
  for (int s = 0; s < 2; ++s)
#pragma unroll
    for (int i = 0; i < 4; ++i) {
      const int qq = quad + s * 4;
      const int rowA = wm * 64 + i * 16 + fr;
      aoff[s][i] = rowA * 64 + (qq ^ (rowA & 7)) * 8;
      const int rowB = wn * 64 + i * 16 + fr;
      boff[s][i] = rowB * 64 + (qq ^ (rowB & 7)) * 8;
    }

  for (int k0 = 0; k0 < K; k0 += 64) {
    // async global -> LDS staging (this K-step's tile). Prior iteration's trailing
    // barrier guarantees all LDS reads of the previous tile completed.
#pragma unroll
    for (int i = 0; i < 4; ++i) {
      __builtin_amdgcn_global_load_lds((g_void*)(aptr[i] + k0),
                                       (lds_void*)(As + ldsOff[i]), 16, 0, 0);
      __builtin_amdgcn_global_load_lds((g_void*)(bptr[i] + k0),
                                       (lds_void*)(Bs + ldsOff[i]), 16, 0, 0);
    }
    __syncthreads();                          // vmcnt(0) drain -> tile visible to all
    bf16x8 af[2][4], bfv[2][4];
#pragma unroll
    for (int s = 0; s < 2; ++s)
#pragma unroll
      for (int i = 0; i < 4; ++i) {
        af[s][i] = *(const bf16x8*)&As[aoff[s][i]];
        bfv[s][i] = *(const bf16x8*)&Bs[boff[s][i]];
      }
#pragma unroll
    for (int s = 0; s < 2; ++s)
#pragma unroll
      for (int i = 0; i < 4; ++i)
#pragma unroll
        for (int j = 0; j < 4; ++j)
          acc[i][j] = __builtin_amdgcn_mfma_f32_16x16x32_bf16(af[s][i], bfv[s][j],
                                                              acc[i][j], 0, 0, 0);
    __syncthreads();                          // reads done before next overwrite
  }

  // ---- epilogue ----
  const int flagv = SCATTER ? flag[0] : 0;
  float bv2[4];
#pragma unroll
  for (int j = 0; j < 4; ++j)
    bv2[j] = biasF[(size_t)e * Nc + colStart + wn * 64 + j * 16 + fr];

  if (SCATTER && flagv) {
    // fp32-output path: exact scalar stores from acc (4-row x 64B chunks, line-dense)
#pragma unroll
    for (int i = 0; i < 4; ++i)
#pragma unroll
      for (int r = 0; r < 4; ++r) {
        const int gr = rowStart + wm * 64 + i * 16 + quad * 4 + r;
        const int crow = rowmap[gr];
        if (crow < 0) continue;
        const size_t cbase = (size_t)crow * Nc + colStart + wn * 64 + fr;
#pragma unroll
        for (int j = 0; j < 4; ++j)
          ((float*)C)[cbase + j * 16] = acc[i][j][r] + bv2[j];
      }
    return;
  }

  __syncthreads();
#pragma unroll
  for (int i = 0; i < 4; ++i)
#pragma unroll
    for (int r = 0; r < 4; ++r) {
      const int row = wm * 64 + i * 16 + quad * 4 + r;   // C/D: row=(lane>>4)*4+reg
#pragma unroll
      for (int j = 0; j < 4; ++j) {
        float v = acc[i][j][r] + bv2[j];
        if (RELU) v = fmaxf(v, 0.f);
        smem[row * CSTRIDE + wn * 64 + j * 16 + fr] = f2bf(v);
      }
    }
  __syncthreads();

#pragma unroll
  for (int it = 0; it < 8; ++it) {
    const int idx = it * 256 + tid;
    const int row = idx >> 4, c16 = idx & 15;
    int crow;
    if (SCATTER) {
      crow = rowmap[rowStart + row];
      if (crow < 0) continue;                 // padding row
    } else {
      crow = rowStart + row - rowBase;        // segment-local
    }
    const uint4 vv = *(const uint4*)&smem[row * CSTRIDE + c16 * 8];
    *(uint4*)&((unsigned short*)C)[(size_t)crow * Nc + colStart + c16 * 8] = vv;
  }
}

extern "C" void kernel_launch(void* const* d_in, const int* in_sizes, int n_in,
                              void* d_out, int out_size, void* d_ws, size_t ws_size,
                              hipStream_t stream) {
  const void* x  = d_in[0];
  const void* Wg = d_in[1];
  const void* bg = d_in[2];
  const void* W0 = d_in[3];
  const void* b0 = d_in[4];
  const void* W1 = d_in[5];
  const void* b1 = d_in[6];
  const void* W2 = d_in[7];
  const void* b2 = d_in[8];

  char* ws = (char*)d_ws;
  // fixed workspace layout (~101.3 MB) + wgF + adaptive h0/h1
  unsigned short* WT0 = (unsigned short*)(ws + 0);            //  8 MB [E][DH][DIN]
  unsigned short* WT1 = (unsigned short*)(ws + 8388608);      // 16 MB [E][DH][DH]
  unsigned short* WT2 = (unsigned short*)(ws + 25165824);     //  8 MB [E][DOUT][DH]
  unsigned short* xc  = (unsigned short*)(ws + 33554432);     // 64 MB [N][DIN] bf16 (flag=1 only)
  float* bf0 = (float*)(ws + 100663296);
  float* bf1 = (float*)(ws + 100696064);
  float* bf2 = (float*)(ws + 100728832);
  int* rowmap = (int*)(ws + 100745216);                       // MP_CAP ints
  int* eidx   = (int*)(ws + 101011456);                       // N ints
  int* counts = (int*)(ws + 101273600);
  int* off    = (int*)(ws + 101273664);
  int* fill   = (int*)(ws + 101273728);
  int* flag   = (int*)(ws + 101273792);
  float* wgF  = (float*)(ws + 101274624);                     // 16 KB [8][512] f32
  const size_t FIXED = 101291008;
  unsigned short* h0 = (unsigned short*)(ws + FIXED);

  // segment sizing: h0+h1 = segBlocks * 524288 B; prefer multiples of 8 for the swizzle
  int segBlocks = 1;
  if (ws_size > FIXED + 524288) {
    size_t sb = (ws_size - FIXED) / 524288;
    segBlocks = (sb > ROW_BLOCKS) ? ROW_BLOCKS : (int)sb;
    if (segBlocks >= 8) segBlocks &= ~7;
  }
  unsigned short* h1 = h0 + (size_t)segBlocks * 128 * DH;
  const int nseg = (ROW_BLOCKS + segBlocks - 1) / segBlocks;

  detect_k<<<1, 256, 0, stream>>>((const unsigned short*)x, flag, counts, fill);

  prep_k<<<161, 256, 0, stream>>>(b0, b1, b2, bf0, bf1, bf2, rowmap, Wg, wgF, flag);

  transpose_all_k<<<4096, 1024, 0, stream>>>(W0, W1, W2, WT0, WT1, WT2, flag);

  gating_k<<<N_TOK / 32, 256, 0, stream>>>(x, wgF, bg, xc, eidx, counts, flag);

  scatter_k<<<N_TOK / 256, 256, 0, stream>>>(eidx, counts, off, fill, rowmap);

  for (int s = 0; s < nseg; ++s) {
    const int rowBase = s * segBlocks * 128;
    // layer 0: gather x rows -> h0 (relu); ncb = DH/128 = 8
    gemm_k<1, 1, 0><<<dim3(8 * segBlocks), 256, 0, stream>>>(
        (const unsigned short*)x, xc, WT0, bf0, h0, rowmap, off, flag, DIN, DH, rowBase, 8, 3);
    // layer 1: h0 -> h1 (relu); ncb = 8
    gemm_k<0, 1, 0><<<dim3(8 * segBlocks), 256, 0, stream>>>(
        h0, h0, WT1, bf1, h1, rowmap, off, flag, DH, DH, rowBase, 8, 3);
    // layer 2: h1 -> out (scatter, bias only); ncb = DOUT/128 = 4
    gemm_k<0, 0, 1><<<dim3(4 * segBlocks), 256, 0, stream>>>(
        h1, h1, WT2, bf2, d_out, rowmap, off, flag, DH, DOUT, rowBase, 4, 2);
  }
}

// Round 8
// 870.853 us; speedup vs baseline: 1.0545x; 1.0182x over previous
//
#include <hip/hip_runtime.h>
#include <stdint.h>

// Problem constants
#define N_TOK 65536
#define DIN   512
#define DH    1024
#define DOUT  512
#define NE    8
#define MP_CAP 66560     // padded row space capacity (N + 8*128, /128)
#define ROW_BLOCKS 520   // MP_CAP / 128
#define CSTRIDE 144      // epilogue C-stage LDS row stride (ushorts): bank-conflict-free

typedef __bf16 bf16x8 __attribute__((ext_vector_type(8)));
typedef float  f32x4  __attribute__((ext_vector_type(4)));

// address-space-qualified pointer types for global_load_lds
typedef __attribute__((address_space(3))) void  lds_void;
typedef const __attribute__((address_space(1))) void g_void;

__device__ __forceinline__ float bf2f(unsigned short u) {
  union { unsigned int i; float f; } v; v.i = ((unsigned int)u) << 16; return v.f;
}
__device__ __forceinline__ unsigned short f2bf(float f) {
  unsigned int u = __builtin_bit_cast(unsigned int, f);
  u += 0x7fffu + ((u >> 16) & 1u);      // RNE
  return (unsigned short)(u >> 16);
}

// ---------------- dtype probe + zero counts/fill (fp32-read-as-ushort has wild exps) --------
__global__ void detect_k(const unsigned short* __restrict__ x, int* __restrict__ flag,
                         int* __restrict__ counts, int* __restrict__ fill) {
  __shared__ int cnt;
  if (threadIdx.x < 8) { counts[threadIdx.x] = 0; fill[threadIdx.x] = 0; }
  if (threadIdx.x == 0) cnt = 0;
  __syncthreads();
  int c = 0;
  for (int i = threadIdx.x; i < 16384; i += 256) {
    const unsigned short u = x[2 * i];
    const int ex = (u >> 7) & 0xFF;
    if (ex > 140) ++c;
  }
  atomicAdd(&cnt, c);
  __syncthreads();
  if (threadIdx.x == 0) flag[0] = (cnt > 512) ? 1 : 0;   // 1 = inputs are fp32
}

// ------- prep: biases -> fp32, rowmap = -1 fill, Wg -> wgF[e][k] f32 (transposed) -------
__global__ __launch_bounds__(256)
void prep_k(const void* __restrict__ b0, const void* __restrict__ b1,
            const void* __restrict__ b2, float* __restrict__ bf0,
            float* __restrict__ bf1, float* __restrict__ bf2,
            int* __restrict__ rowmap, const void* __restrict__ Wg,
            float* __restrict__ wgF, const int* __restrict__ flag) {
  const int b = blockIdx.x;
  if (b < 65) {                       // rowmap: 66560 ints = 65 blocks * 256 * int4
    const int i = (b * 256 + threadIdx.x) * 4;
    *(int4*)&rowmap[i] = (int4){-1, -1, -1, -1};
    return;
  }
  const int fv = flag[0];
  if (b < 145) {                      // biases: 20480 elements
    const int i = (b - 65) * 256 + threadIdx.x;
    const void* src; float* dst; int li;
    if (i < NE * DH) { src = b0; dst = bf0; li = i; }
    else if (i < 2 * NE * DH) { src = b1; dst = bf1; li = i - NE * DH; }
    else { src = b2; dst = bf2; li = i - 2 * NE * DH; }
    dst[li] = fv ? ((const float*)src)[li] : bf2f(((const unsigned short*)src)[li]);
    return;
  }
  // wgF[e][k] = Wg[k][e], f32: 4096 elements in 16 blocks
  const int idx = (b - 145) * 256 + threadIdx.x;
  const int e = idx >> 9, k = idx & 511;
  wgF[idx] = fv ? ((const float*)Wg)[k * 8 + e]
                : bf2f(((const unsigned short*)Wg)[k * 8 + e]);
}

// ---------------- all three weight transposes in one launch ----------------
// W[e][K][Nn] -> WT[e][Nn][K] (bf16 out); tile decode from 1-D grid.
__global__ __launch_bounds__(1024)
void transpose_all_k(const void* __restrict__ W0, const void* __restrict__ W1,
                     const void* __restrict__ W2, unsigned short* __restrict__ WT0,
                     unsigned short* __restrict__ WT1, unsigned short* __restrict__ WT2,
                     const int* __restrict__ flag) {
  __shared__ unsigned short tile[64][65];
  const int fv = flag[0];
  int b = blockIdx.x;
  const void* W; unsigned short* WT; int K, Nn, e, n0, k0;
  if (b < 1024) {            // W0: per-expert 16 n-tiles x 8 k-tiles
    W = W0; WT = WT0; K = DIN; Nn = DH;
    e = b >> 7; const int r = b & 127; n0 = (r & 15) * 64; k0 = (r >> 4) * 64;
  } else if (b < 3072) {     // W1: 16 x 16
    b -= 1024; W = W1; WT = WT1; K = DH; Nn = DH;
    e = b >> 8; const int r = b & 255; n0 = (r & 15) * 64; k0 = (r >> 4) * 64;
  } else {                   // W2: 8 n-tiles x 16 k-tiles
    b -= 3072; W = W2; WT = WT2; K = DH; Nn = DOUT;
    e = b >> 7; const int r = b & 127; n0 = (r & 7) * 64; k0 = (r >> 3) * 64;
  }
  const size_t base = (size_t)e * K * Nn;
  unsigned short* dst = WT + base;
  const int tx = threadIdx.x & 63, ty = threadIdx.x >> 6;
#pragma unroll
  for (int i = 0; i < 4; ++i) {
    const size_t idx = base + (size_t)(k0 + ty + i * 16) * Nn + n0 + tx;
    tile[ty + i * 16][tx] = fv ? f2bf(((const float*)W)[idx])
                               : ((const unsigned short*)W)[idx];
  }
  __syncthreads();
#pragma unroll
  for (int i = 0; i < 4; ++i)
    dst[(size_t)(n0 + ty + i * 16) * K + k0 + tx] = tile[tx][ty + i * 16];
}

// ---------------- fused gating: logits(fp64) + argmax + xc(bf16) + counts ----------------
// Block = 32 tokens, two 256-col chunks. Per chunk: 256 threads stage 32x256 f32 into
// LDS COALESCED (x fetched exactly once; xc bf16 write fused in the same pass), sync,
// then each wave dots its 8 tokens from LDS: lane (tok,e) does 64 x {ds_read_b128 +
// L1-hot wgF f32x4 + 4 dfma}. Round-7's dot loop re-read x per-lane from global at
// ~900cy serialized (VGPR=32, FETCH 120MB): this replaces those with 120cy LDS hits.
// LDS row stride 260 f32: dot-read banks (4*tok+4*k4)%32 distinct across the 8 token
// groups (conflict-free; 8-way same-address broadcast is free). fp64 chain order is
// IDENTICAL to the passing round-7 kernel (k = j mod 4 ascending chains, (s0+s1)+(s2+s3));
// chunking appends, not reorders. Argmax butterfly = (max, min-idx) == np.argmax.
__global__ __launch_bounds__(256)
void gating_k(const void* __restrict__ x, const float* __restrict__ wgF,
              const void* __restrict__ bg, unsigned short* __restrict__ xc,
              int* __restrict__ eidx, int* __restrict__ counts,
              const int* __restrict__ flag) {
  __shared__ float xs[32 * 260];     // 33280 B
  __shared__ int hist[8];
  const int tid = threadIdx.x;
  if (tid < 8) hist[tid] = 0;

  const int tok0 = blockIdx.x * 32;
  const int fv = flag[0];
  const int wv = tid >> 6, lane = tid & 63;
  const int tokL = (wv << 3) + (lane >> 3);   // wave wv owns tokens wv*8 .. wv*8+7
  const int e = lane & 7;
  const float* wrow = wgF + e * DIN;

  double s0 = 0.0, s1 = 0.0, s2 = 0.0, s3 = 0.0;

  for (int c = 0; c < 2; ++c) {
    // ---- stage 32 rows x 256 cols into LDS (coalesced); fuse xc write when fv ----
    if (fv) {
      const float* xf = (const float*)x;
#pragma unroll
      for (int j = 0; j < 8; ++j) {
        const int idx = j * 256 + tid;          // 0..2047
        const int row = idx >> 6, c4 = (idx & 63) * 4;
        const size_t gi = (size_t)(tok0 + row) * DIN + c * 256 + c4;
        const f32x4 v = *(const f32x4*)&xf[gi];
        *(f32x4*)&xs[row * 260 + c4] = v;
        unsigned short o[4] = {f2bf(v[0]), f2bf(v[1]), f2bf(v[2]), f2bf(v[3])};
        *(uint2*)&xc[gi] = *(const uint2*)o;
      }
    } else {
      const unsigned short* xu = (const unsigned short*)x;
#pragma unroll
      for (int j = 0; j < 8; ++j) {
        const int idx = j * 256 + tid;
        const int row = idx >> 6, c4 = (idx & 63) * 4;
        const size_t gi = (size_t)(tok0 + row) * DIN + c * 256 + c4;
        const ushort4 u = *(const ushort4*)&xu[gi];
        const f32x4 v = {bf2f(u.x), bf2f(u.y), bf2f(u.z), bf2f(u.w)};
        *(f32x4*)&xs[row * 260 + c4] = v;
      }
    }
    __syncthreads();

    // ---- dot over this chunk from LDS ----
    const float* xr = xs + tokL * 260;
    const float* wc = wrow + c * 256;
#pragma unroll 8
    for (int k4 = 0; k4 < 64; ++k4) {
      const f32x4 xv = *(const f32x4*)&xr[k4 * 4];
      const f32x4 wv2 = *(const f32x4*)&wc[k4 * 4];
      s0 += (double)xv[0] * (double)wv2[0];
      s1 += (double)xv[1] * (double)wv2[1];
      s2 += (double)xv[2] * (double)wv2[2];
      s3 += (double)xv[3] * (double)wv2[3];
    }
    __syncthreads();                           // before next chunk overwrites xs
  }

  double v = (s0 + s1) + (s2 + s3);
  v += fv ? (double)((const float*)bg)[e]
          : (double)bf2f(((const unsigned short*)bg)[e]);
  int be = e;
#pragma unroll
  for (int d = 1; d <= 4; d <<= 1) {           // butterfly within the 8-lane expert group
    const double vo = __shfl_xor(v, d, 64);
    const int eo = __shfl_xor(be, d, 64);
    if (vo > v || (vo == v && eo < be)) { v = vo; be = eo; }
  }
  if (e == 0) {                                // one lane per token
    eidx[tok0 + tokL] = be;
    atomicAdd(&hist[be], 1);
  }
  __syncthreads();
  if (tid < 8 && hist[tid]) atomicAdd(&counts[tid], hist[tid]);
}

// ---------------- scatter tokens into rowmap (local prefix from counts) ----------------
__global__ __launch_bounds__(256)
void scatter_k(const int* __restrict__ eidx, const int* __restrict__ counts,
               int* __restrict__ off_g, int* __restrict__ fill,
               int* __restrict__ rowmap) {
  int off[8];
  {
    int a = 0;
#pragma unroll
    for (int e2 = 0; e2 < 8; ++e2) { off[e2] = a; a += (counts[e2] + 127) & ~127; }
    if (blockIdx.x == 0 && threadIdx.x == 0) {
      off_g[0] = 0;
      int aa = 0;
#pragma unroll
      for (int e2 = 0; e2 < 8; ++e2) { aa += (counts[e2] + 127) & ~127; off_g[e2 + 1] = aa; }
    }
  }
  const int t = blockIdx.x * 256 + threadIdx.x;
  const int lane = threadIdx.x & 63;
  const int e = eidx[t];
#pragma unroll
  for (int ex = 0; ex < 8; ++ex) {
    unsigned long long m = __ballot(e == ex);
    if (e == ex) {
      const unsigned long long lt = (1ULL << lane) - 1ULL;
      const int rank = __popcll(m & lt);
      const int leader = __ffsll((unsigned long long)m) - 1;
      int base = 0;
      if (lane == leader) base = atomicAdd(&fill[ex], (int)__popcll(m));
      base = __shfl(base, leader, 64);
      rowmap[off[ex] + base + rank] = t;
    }
  }
}

// ---------------- grouped GEMM: C[128 x 128] per block, K-step 64 ----------------
// (unchanged — global_load_lds width=16, Rule-21 swizzle)
template <int GATHER, int RELU, int SCATTER>
__global__ __launch_bounds__(256, 2)
void gemm_k(const unsigned short* __restrict__ A, const unsigned short* __restrict__ Axc,
            const unsigned short* __restrict__ BT,
            const float* __restrict__ biasF, void* __restrict__ C,
            const int* __restrict__ rowmap, const int* __restrict__ off,
            const int* __restrict__ flag, const int K, const int Nc, const int rowBase,
            const int ncb, const int lncb) {
  __shared__ __align__(16) unsigned short smem[128 * CSTRIDE];  // 36 KB
  unsigned short* As = smem;                 // staging: 128x64 = 16 KB
  unsigned short* Bs = smem + 128 * 64;      // staging: 128x64 = 16 KB

  // ---- swizzled block -> (rowg, col) ----
  const int segBlocksLocal = gridDim.x >> lncb;
  const int fullRows = segBlocksLocal & ~7;
  const int fullBlocks = fullRows << lncb;
  int col, rowg;
  {
    const int p = blockIdx.x;
    if (p < fullBlocks) {
      const int xcd = p & 7, qq = p >> 3;
      col = qq & (ncb - 1);
      rowg = ((qq >> lncb) << 3) + xcd;
    } else {
      const int r = p - fullBlocks;
      col = r & (ncb - 1);
      rowg = fullRows + (r >> lncb);
    }
  }

  const int Mp = off[8];
  const int rowStart = rowBase + rowg * 128;
  if (rowStart >= Mp) return;
  int e = 0;
#pragma unroll
  for (int j = 1; j <= 8; ++j) e += (off[j] <= rowStart) ? 1 : 0;

  const int colStart = col * 128;
  const int tid = threadIdx.x;
  const int w = tid >> 6, lane = tid & 63;
  const int subrow = lane >> 3;
  const int q = lane & 7;
  const int slot = q ^ subrow;               // inverse-swizzled global chunk index

  const unsigned short* Ause = (GATHER && flag[0]) ? Axc : A;
  const unsigned short* Be = BT + (size_t)e * Nc * K;

  // per-lane global source pointers (chunk `slot`), wave-uniform LDS dest offsets
  const unsigned short* aptr[4];
  const unsigned short* bptr[4];
  int ldsOff[4];
#pragma unroll
  for (int i = 0; i < 4; ++i) {
    const int r = i * 32 + w * 8 + subrow;
    int arow;
    if (GATHER) {
      arow = rowmap[rowStart + r];
      if (arow < 0) arow = 0;                 // padding row: load safe garbage
    } else {
      arow = rowStart + r - rowBase;          // segment-local
    }
    aptr[i] = Ause + (size_t)arow * K + slot * 8;
    bptr[i] = Be + (size_t)(colStart + r) * K + slot * 8;
    ldsOff[i] = (i * 32 + w * 8) * 64;        // linear dest: 8 rows x 128 B per call
  }

  const int wm = w >> 1, wn = w & 1;
  const int fr = lane & 15, quad = lane >> 4;

  f32x4 acc[4][4];
#pragma unroll
  for (int i = 0; i < 4; ++i)
#pragma unroll
    for (int j = 0; j < 4; ++j) acc[i][j] = (f32x4){0.f, 0.f, 0.f, 0.f};

  int aoff[2][4], boff[2][4];
#pragma unroll
  for (int s = 0; s < 2; ++s)
#pragma unroll
    for (int i = 0; i < 4; ++i) {
      const int qq = quad + s * 4;
      const int rowA = wm * 64 + i * 16 + fr;
      aoff[s][i] = rowA * 64 + (qq ^ (rowA & 7)) * 8;
      const int rowB = wn * 64 + i * 16 + fr;
      boff[s][i] = rowB * 64 + (qq ^ (rowB & 7)) * 8;
    }

  for (int k0 = 0; k0 < K; k0 += 64) {
    // async global -> LDS staging (this K-step's tile). Prior iteration's trailing
    // barrier guarantees all LDS reads of the previous tile completed.
#pragma unroll
    for (int i = 0; i < 4; ++i) {
      __builtin_amdgcn_global_load_lds((g_void*)(aptr[i] + k0),
                                       (lds_void*)(As + ldsOff[i]), 16, 0, 0);
      __builtin_amdgcn_global_load_lds((g_void*)(bptr[i] + k0),
                                       (lds_void*)(Bs + ldsOff[i]), 16, 0, 0);
    }
    __syncthreads();                          // vmcnt(0) drain -> tile visible to all
    bf16x8 af[2][4], bfv[2][4];
#pragma unroll
    for (int s = 0; s < 2; ++s)
#pragma unroll
      for (int i = 0; i < 4; ++i) {
        af[s][i] = *(const bf16x8*)&As[aoff[s][i]];
        bfv[s][i] = *(const bf16x8*)&Bs[boff[s][i]];
      }
#pragma unroll
    for (int s = 0; s < 2; ++s)
#pragma unroll
      for (int i = 0; i < 4; ++i)
#pragma unroll
        for (int j = 0; j < 4; ++j)
          acc[i][j] = __builtin_amdgcn_mfma_f32_16x16x32_bf16(af[s][i], bfv[s][j],
                                                              acc[i][j], 0, 0, 0);
    __syncthreads();                          // reads done before next overwrite
  }

  // ---- epilogue ----
  const int flagv = SCATTER ? flag[0] : 0;
  float bv2[4];
#pragma unroll
  for (int j = 0; j < 4; ++j)
    bv2[j] = biasF[(size_t)e * Nc + colStart + wn * 64 + j * 16 + fr];

  if (SCATTER && flagv) {
    // fp32-output path: exact scalar stores from acc (4-row x 64B chunks, line-dense)
#pragma unroll
    for (int i = 0; i < 4; ++i)
#pragma unroll
      for (int r = 0; r < 4; ++r) {
        const int gr = rowStart + wm * 64 + i * 16 + quad * 4 + r;
        const int crow = rowmap[gr];
        if (crow < 0) continue;
        const size_t cbase = (size_t)crow * Nc + colStart + wn * 64 + fr;
#pragma unroll
        for (int j = 0; j < 4; ++j)
          ((float*)C)[cbase + j * 16] = acc[i][j][r] + bv2[j];
      }
    return;
  }

  __syncthreads();
#pragma unroll
  for (int i = 0; i < 4; ++i)
#pragma unroll
    for (int r = 0; r < 4; ++r) {
      const int row = wm * 64 + i * 16 + quad * 4 + r;   // C/D: row=(lane>>4)*4+reg
#pragma unroll
      for (int j = 0; j < 4; ++j) {
        float v = acc[i][j][r] + bv2[j];
        if (RELU) v = fmaxf(v, 0.f);
        smem[row * CSTRIDE + wn * 64 + j * 16 + fr] = f2bf(v);
      }
    }
  __syncthreads();

#pragma unroll
  for (int it = 0; it < 8; ++it) {
    const int idx = it * 256 + tid;
    const int row = idx >> 4, c16 = idx & 15;
    int crow;
    if (SCATTER) {
      crow = rowmap[rowStart + row];
      if (crow < 0) continue;                 // padding row
    } else {
      crow = rowStart + row - rowBase;        // segment-local
    }
    const uint4 vv = *(const uint4*)&smem[row * CSTRIDE + c16 * 8];
    *(uint4*)&((unsigned short*)C)[(size_t)crow * Nc + colStart + c16 * 8] = vv;
  }
}

extern "C" void kernel_launch(void* const* d_in, const int* in_sizes, int n_in,
                              void* d_out, int out_size, void* d_ws, size_t ws_size,
                              hipStream_t stream) {
  const void* x  = d_in[0];
  const void* Wg = d_in[1];
  const void* bg = d_in[2];
  const void* W0 = d_in[3];
  const void* b0 = d_in[4];
  const void* W1 = d_in[5];
  const void* b1 = d_in[6];
  const void* W2 = d_in[7];
  const void* b2 = d_in[8];

  char* ws = (char*)d_ws;
  // fixed workspace layout (~101.3 MB) + wgF + adaptive h0/h1
  unsigned short* WT0 = (unsigned short*)(ws + 0);            //  8 MB [E][DH][DIN]
  unsigned short* WT1 = (unsigned short*)(ws + 8388608);      // 16 MB [E][DH][DH]
  unsigned short* WT2 = (unsigned short*)(ws + 25165824);     //  8 MB [E][DOUT][DH]
  unsigned short* xc  = (unsigned short*)(ws + 33554432);     // 64 MB [N][DIN] bf16 (flag=1 only)
  float* bf0 = (float*)(ws + 100663296);
  float* bf1 = (float*)(ws + 100696064);
  float* bf2 = (float*)(ws + 100728832);
  int* rowmap = (int*)(ws + 100745216);                       // MP_CAP ints
  int* eidx   = (int*)(ws + 101011456);                       // N ints
  int* counts = (int*)(ws + 101273600);
  int* off    = (int*)(ws + 101273664);
  int* fill   = (int*)(ws + 101273728);
  int* flag   = (int*)(ws + 101273792);
  float* wgF  = (float*)(ws + 101274624);                     // 16 KB [8][512] f32
  const size_t FIXED = 101291008;
  unsigned short* h0 = (unsigned short*)(ws + FIXED);

  // segment sizing: h0+h1 = segBlocks * 524288 B; prefer multiples of 8 for the swizzle
  int segBlocks = 1;
  if (ws_size > FIXED + 524288) {
    size_t sb = (ws_size - FIXED) / 524288;
    segBlocks = (sb > ROW_BLOCKS) ? ROW_BLOCKS : (int)sb;
    if (segBlocks >= 8) segBlocks &= ~7;
  }
  unsigned short* h1 = h0 + (size_t)segBlocks * 128 * DH;
  const int nseg = (ROW_BLOCKS + segBlocks - 1) / segBlocks;

  detect_k<<<1, 256, 0, stream>>>((const unsigned short*)x, flag, counts, fill);

  prep_k<<<161, 256, 0, stream>>>(b0, b1, b2, bf0, bf1, bf2, rowmap, Wg, wgF, flag);

  transpose_all_k<<<4096, 1024, 0, stream>>>(W0, W1, W2, WT0, WT1, WT2, flag);

  gating_k<<<N_TOK / 32, 256, 0, stream>>>(x, wgF, bg, xc, eidx, counts, flag);

  scatter_k<<<N_TOK / 256, 256, 0, stream>>>(eidx, counts, off, fill, rowmap);

  for (int s = 0; s < nseg; ++s) {
    const int rowBase = s * segBlocks * 128;
    // layer 0: gather x rows -> h0 (relu); ncb = DH/128 = 8
    gemm_k<1, 1, 0><<<dim3(8 * segBlocks), 256, 0, stream>>>(
        (const unsigned short*)x, xc, WT0, bf0, h0, rowmap, off, flag, DIN, DH, rowBase, 8, 3);
    // layer 1: h0 -> h1 (relu); ncb = 8
    gemm_k<0, 1, 0><<<dim3(8 * segBlocks), 256, 0, stream>>>(
        h0, h0, WT1, bf1, h1, rowmap, off, flag, DH, DH, rowBase, 8, 3);
    // layer 2: h1 -> out (scatter, bias only); ncb = DOUT/128 = 4
    gemm_k<0, 0, 1><<<dim3(4 * segBlocks), 256, 0, stream>>>(
        h1, h1, WT2, bf2, d_out, rowmap, off, flag, DH, DOUT, rowBase, 4, 2);
  }
}